// Round 1
// baseline (6275.359 us; speedup 1.0000x reference)
//
#include <hip/hip_runtime.h>
#include <math.h>

#define T_STEPS 24
#define F_IN 10
#define HDIM 128
#define E_EDGES 80000
#define B_BATCH 8
#define N_NODES 5000
#define BN_TOTAL 40000
#define BE 640000
#define NE 680000
#define G3 384

__device__ __forceinline__ float sigmoidf_(float v) { return 1.f / (1.f + __expf(-v)); }
__device__ __forceinline__ float tanhf_(float v) { return 1.f - 2.f / (1.f + __expf(2.f * v)); }

// ---------------- weight pre-transpose: w[j][k] -> wt[k][j] ----------------
// wt layout (floats): [0,3840) wT_ih0 ; [3840,52992) wT_hh0 ; [52992,102144) wT_ih1 ; [102144,151296) wT_hh1
__global__ void transpose_w(const float* __restrict__ wih0, const float* __restrict__ whh0,
                            const float* __restrict__ wih1, const float* __restrict__ whh1,
                            float* __restrict__ wt) {
    int i = blockIdx.x * 256 + threadIdx.x;
    if (i < 3840) { int f = i / G3, j = i % G3; wt[i] = wih0[j * F_IN + f]; return; }
    int i2 = i - 3840;
    if (i2 < 49152) { int k = i2 / G3, j = i2 % G3; wt[i] = whh0[j * HDIM + k]; return; }
    i2 -= 49152;
    if (i2 < 49152) { int k = i2 / G3, j = i2 % G3; wt[i] = wih1[j * HDIM + k]; return; }
    i2 -= 49152;
    if (i2 < 49152) { int k = i2 / G3, j = i2 % G3; wt[i] = whh1[j * HDIM + k]; return; }
}

// ---------------- fused 2-layer GRU, 32 sequences / block ----------------
__global__ __launch_bounds__(256, 3) void gru_kernel(
    const float* __restrict__ x, const float* __restrict__ wt,
    const float* __restrict__ bih0, const float* __restrict__ bhh0,
    const float* __restrict__ bih1, const float* __restrict__ bhh1,
    float* __restrict__ temporal) {
    __shared__ float h1[32][HDIM];
    __shared__ float h2[32][HDIM];
    const int t = threadIdx.x;
    const int jj = t & 127;
    const int s0 = (t >> 7) * 16;
    const long seqbase = (long)blockIdx.x * 32;

    const float* wt_ih0 = wt;
    const float* wt_hh0 = wt + 3840;
    const float* wt_ih1 = wt + 52992;
    const float* wt_hh1 = wt + 102144;

    for (int i = t; i < 32 * HDIM; i += 256) { (&h1[0][0])[i] = 0.f; (&h2[0][0])[i] = 0.f; }

    const float br0 = bih0[jj] + bhh0[jj];
    const float bz0 = bih0[128 + jj] + bhh0[128 + jj];
    const float bin0 = bih0[256 + jj];
    const float bhn0 = bhh0[256 + jj];
    const float br1 = bih1[jj] + bhh1[jj];
    const float bz1 = bih1[128 + jj] + bhh1[128 + jj];
    const float bin1 = bih1[256 + jj];
    const float bhn1 = bhh1[256 + jj];
    __syncthreads();

    for (int tt = 0; tt < T_STEPS; ++tt) {
        // ===== layer 0 =====
        float racc[16], zacc[16], nacc[16], xn[16];
#pragma unroll
        for (int i = 0; i < 16; ++i) { racc[i] = 0.f; zacc[i] = 0.f; nacc[i] = 0.f; xn[i] = 0.f; }
        for (int k4 = 0; k4 < HDIM; k4 += 4) {
            float wr[4], wz[4], wn[4];
#pragma unroll
            for (int q = 0; q < 4; ++q) {
                const float* wrow = wt_hh0 + (k4 + q) * G3;
                wr[q] = wrow[jj]; wz[q] = wrow[128 + jj]; wn[q] = wrow[256 + jj];
            }
#pragma unroll
            for (int i = 0; i < 16; ++i) {
                const float4 h4 = *(const float4*)&h1[s0 + i][k4];
                racc[i] += h4.x * wr[0] + h4.y * wr[1] + h4.z * wr[2] + h4.w * wr[3];
                zacc[i] += h4.x * wz[0] + h4.y * wz[1] + h4.z * wz[2] + h4.w * wz[3];
                nacc[i] += h4.x * wn[0] + h4.y * wn[1] + h4.z * wn[2] + h4.w * wn[3];
            }
        }
        for (int f = 0; f < F_IN; ++f) {
            const float* wrow = wt_ih0 + f * G3;
            const float wr = wrow[jj], wz = wrow[128 + jj], wn = wrow[256 + jj];
#pragma unroll
            for (int i = 0; i < 16; ++i) {
                const float xv = x[(seqbase + s0 + i) * (T_STEPS * F_IN) + tt * F_IN + f];
                racc[i] += xv * wr; zacc[i] += xv * wz; xn[i] += xv * wn;
            }
        }
        float hnew[16];
#pragma unroll
        for (int i = 0; i < 16; ++i) {
            const float r = sigmoidf_(racc[i] + br0);
            const float z = sigmoidf_(zacc[i] + bz0);
            const float n = tanhf_(xn[i] + bin0 + r * (nacc[i] + bhn0));
            hnew[i] = (1.f - z) * n + z * h1[s0 + i][jj];
        }
        __syncthreads();
#pragma unroll
        for (int i = 0; i < 16; ++i) h1[s0 + i][jj] = hnew[i];
        __syncthreads();

        // ===== layer 1 =====
        float racc1[16], zacc1[16], ni[16], nh[16];
#pragma unroll
        for (int i = 0; i < 16; ++i) { racc1[i] = 0.f; zacc1[i] = 0.f; ni[i] = 0.f; nh[i] = 0.f; }
        for (int k4 = 0; k4 < HDIM; k4 += 4) {
            float wir[4], wiz[4], win[4], whr[4], whz[4], whn[4];
#pragma unroll
            for (int q = 0; q < 4; ++q) {
                const float* wi = wt_ih1 + (k4 + q) * G3;
                const float* wh = wt_hh1 + (k4 + q) * G3;
                wir[q] = wi[jj]; wiz[q] = wi[128 + jj]; win[q] = wi[256 + jj];
                whr[q] = wh[jj]; whz[q] = wh[128 + jj]; whn[q] = wh[256 + jj];
            }
#pragma unroll
            for (int i = 0; i < 16; ++i) {
                const float4 a4 = *(const float4*)&h1[s0 + i][k4];
                const float4 b4 = *(const float4*)&h2[s0 + i][k4];
                racc1[i] += a4.x * wir[0] + a4.y * wir[1] + a4.z * wir[2] + a4.w * wir[3]
                          + b4.x * whr[0] + b4.y * whr[1] + b4.z * whr[2] + b4.w * whr[3];
                zacc1[i] += a4.x * wiz[0] + a4.y * wiz[1] + a4.z * wiz[2] + a4.w * wiz[3]
                          + b4.x * whz[0] + b4.y * whz[1] + b4.z * whz[2] + b4.w * whz[3];
                ni[i] += a4.x * win[0] + a4.y * win[1] + a4.z * win[2] + a4.w * win[3];
                nh[i] += b4.x * whn[0] + b4.y * whn[1] + b4.z * whn[2] + b4.w * whn[3];
            }
        }
#pragma unroll
        for (int i = 0; i < 16; ++i) {
            const float r = sigmoidf_(racc1[i] + br1);
            const float z = sigmoidf_(zacc1[i] + bz1);
            const float n = tanhf_(ni[i] + bin1 + r * (nh[i] + bhn1));
            hnew[i] = (1.f - z) * n + z * h2[s0 + i][jj];
        }
        __syncthreads();
#pragma unroll
        for (int i = 0; i < 16; ++i) h2[s0 + i][jj] = hnew[i];
        __syncthreads();
    }
#pragma unroll
    for (int i = 0; i < 16; ++i)
        temporal[(seqbase + s0 + i) * HDIM + jj] = h2[s0 + i][jj];
}

// ---------------- CSR build ----------------
__global__ void csr_count(const int* __restrict__ edge1, int* __restrict__ cnt) {
    int e = blockIdx.x * 256 + threadIdx.x;
    if (e >= NE) return;
    int d;
    if (e < BE) { int b = e / E_EDGES; d = edge1[e - b * E_EDGES] + b * N_NODES; }
    else d = e - BE;
    atomicAdd(&cnt[d], 1);
}

__global__ void csr_scan(const int* cnt, int* offs, int* curs) {
    __shared__ int part[1024];
    const int t = threadIdx.x;
    const int base = t * 40;
    int end = base + 40; if (end > BN_TOTAL) end = BN_TOTAL;
    int s = 0;
    for (int i = base; i < end; ++i) s += cnt[i];
    part[t] = s;
    __syncthreads();
    for (int off = 1; off < 1024; off <<= 1) {
        int v = (t >= off) ? part[t - off] : 0;
        __syncthreads();
        part[t] += v;
        __syncthreads();
    }
    int run = part[t] - s;
    for (int i = base; i < end; ++i) {
        int c = cnt[i];
        offs[i] = run; curs[i] = run; run += c;
    }
    if (t == 1023) offs[BN_TOTAL] = NE;
}

__global__ void csr_fill(const int* __restrict__ edge1, int* __restrict__ curs, int* __restrict__ esort) {
    int e = blockIdx.x * 256 + threadIdx.x;
    if (e >= NE) return;
    int d;
    if (e < BE) { int b = e / E_EDGES; d = edge1[e - b * E_EDGES] + b * N_NODES; }
    else d = e - BE;
    int pos = atomicAdd(&curs[d], 1);
    esort[pos] = e;
}

// ---------------- GAT: wh = feat @ W.T  (tiled 64x64, K=128) ----------------
__global__ __launch_bounds__(256) void gat_gemm(const float* __restrict__ feat,
                                                const float* __restrict__ W,
                                                float* __restrict__ wh) {
    __shared__ float As[64][129];
    __shared__ float Bs[64][129];
    const int t = threadIdx.x;
    const int i0 = blockIdx.x * 64;
    const int j0 = blockIdx.y * 64;
    for (int idx = t; idx < 64 * 128; idx += 256) {
        int r = idx >> 7, c = idx & 127;
        As[r][c] = feat[(size_t)(i0 + r) * 128 + c];
        Bs[r][c] = W[(size_t)(j0 + r) * 128 + c];
    }
    __syncthreads();
    const int tr = (t >> 4) * 4;
    const int tc = (t & 15) * 4;
    float acc[4][4] = {};
    for (int k = 0; k < 128; ++k) {
        float a[4], b[4];
#pragma unroll
        for (int q = 0; q < 4; ++q) { a[q] = As[tr + q][k]; b[q] = Bs[tc + q][k]; }
#pragma unroll
        for (int i = 0; i < 4; ++i)
#pragma unroll
            for (int j = 0; j < 4; ++j) acc[i][j] += a[i] * b[j];
    }
#pragma unroll
    for (int i = 0; i < 4; ++i)
#pragma unroll
        for (int j = 0; j < 4; ++j)
            wh[(size_t)(i0 + tr + i) * 512 + j0 + tc + j] = acc[i][j];
}

// ---------------- per-node alpha_src / alpha_dst ----------------
__global__ __launch_bounds__(256) void gat_alpha(const float* __restrict__ wh,
                                                 const float* __restrict__ asrc, const float* __restrict__ adst,
                                                 float* __restrict__ AS, float* __restrict__ AD) {
    const int lane = threadIdx.x & 63;
    const int node = blockIdx.x * 4 + (threadIdx.x >> 6);
    const float* r = wh + (size_t)node * 512;
    float ps[4], pd[4];
#pragma unroll
    for (int hd = 0; hd < 4; ++hd) {
        float w0 = r[hd * 128 + lane], w1 = r[hd * 128 + 64 + lane];
        ps[hd] = w0 * asrc[hd * 128 + lane] + w1 * asrc[hd * 128 + 64 + lane];
        pd[hd] = w0 * adst[hd * 128 + lane] + w1 * adst[hd * 128 + 64 + lane];
    }
#pragma unroll
    for (int off = 32; off > 0; off >>= 1) {
#pragma unroll
        for (int hd = 0; hd < 4; ++hd) {
            ps[hd] += __shfl_down(ps[hd], off);
            pd[hd] += __shfl_down(pd[hd], off);
        }
    }
    if (lane == 0) {
#pragma unroll
        for (int hd = 0; hd < 4; ++hd) { AS[node * 4 + hd] = ps[hd]; AD[node * 4 + hd] = pd[hd]; }
    }
}

__device__ __forceinline__ int decode_src(int eid, const int* __restrict__ edge0) {
    if (eid < BE) { int b = eid / E_EDGES; return edge0[eid - b * E_EDGES] + b * N_NODES; }
    return eid - BE;
}

// ---------------- per-node softmax attention + aggregate (one wave / node) ----------------
__global__ __launch_bounds__(256) void gat_aggregate(const float* __restrict__ wh,
                                                     const float* __restrict__ AS, const float* __restrict__ AD,
                                                     const int* __restrict__ offs, const int* __restrict__ esort,
                                                     const int* __restrict__ edge0, const float* __restrict__ bias,
                                                     float* __restrict__ outf) {
    const int lane = threadIdx.x & 63;
    const int d = blockIdx.x * 4 + (threadIdx.x >> 6);
    const int e0 = offs[d], e1 = offs[d + 1];
    const float ad0 = AD[d * 4 + 0], ad1 = AD[d * 4 + 1], ad2 = AD[d * 4 + 2], ad3 = AD[d * 4 + 3];
    float mx0 = -1e30f, mx1 = -1e30f, mx2 = -1e30f, mx3 = -1e30f;
    for (int e = e0; e < e1; ++e) {
        const int src = decode_src(esort[e], edge0);
        float v0 = AS[src * 4 + 0] + ad0; v0 = v0 > 0.f ? v0 : 0.2f * v0; mx0 = fmaxf(mx0, v0);
        float v1 = AS[src * 4 + 1] + ad1; v1 = v1 > 0.f ? v1 : 0.2f * v1; mx1 = fmaxf(mx1, v1);
        float v2 = AS[src * 4 + 2] + ad2; v2 = v2 > 0.f ? v2 : 0.2f * v2; mx2 = fmaxf(mx2, v2);
        float v3 = AS[src * 4 + 3] + ad3; v3 = v3 > 0.f ? v3 : 0.2f * v3; mx3 = fmaxf(mx3, v3);
    }
    float den0 = 0.f, den1 = 0.f, den2 = 0.f, den3 = 0.f;
    float acc[8] = {0.f, 0.f, 0.f, 0.f, 0.f, 0.f, 0.f, 0.f};
    for (int e = e0; e < e1; ++e) {
        const int src = decode_src(esort[e], edge0);
        float v0 = AS[src * 4 + 0] + ad0; v0 = v0 > 0.f ? v0 : 0.2f * v0; float ex0 = __expf(v0 - mx0); den0 += ex0;
        float v1 = AS[src * 4 + 1] + ad1; v1 = v1 > 0.f ? v1 : 0.2f * v1; float ex1 = __expf(v1 - mx1); den1 += ex1;
        float v2 = AS[src * 4 + 2] + ad2; v2 = v2 > 0.f ? v2 : 0.2f * v2; float ex2 = __expf(v2 - mx2); den2 += ex2;
        float v3 = AS[src * 4 + 3] + ad3; v3 = v3 > 0.f ? v3 : 0.2f * v3; float ex3 = __expf(v3 - mx3); den3 += ex3;
        const float* wr = wh + (size_t)src * 512;
        acc[0] += ex0 * wr[lane];        acc[1] += ex0 * wr[64 + lane];
        acc[2] += ex1 * wr[128 + lane];  acc[3] += ex1 * wr[192 + lane];
        acc[4] += ex2 * wr[256 + lane];  acc[5] += ex2 * wr[320 + lane];
        acc[6] += ex3 * wr[384 + lane];  acc[7] += ex3 * wr[448 + lane];
    }
    den0 += 1e-16f; den1 += 1e-16f; den2 += 1e-16f; den3 += 1e-16f;
    const float o0 = 0.25f * (acc[0] / den0 + acc[2] / den1 + acc[4] / den2 + acc[6] / den3) + bias[lane];
    const float o1 = 0.25f * (acc[1] / den0 + acc[3] / den1 + acc[5] / den2 + acc[7] / den3) + bias[64 + lane];
    outf[(size_t)d * 128 + lane] = fmaxf(o0, 0.f);
    outf[(size_t)d * 128 + 64 + lane] = fmaxf(o1, 0.f);
}

// ---------------- final FC: one wave / node ----------------
__global__ __launch_bounds__(256) void fc_kernel(const float* __restrict__ s,
                                                 const float* __restrict__ fw, const float* __restrict__ fb,
                                                 float* __restrict__ out) {
    const int lane = threadIdx.x & 63;
    const int i = blockIdx.x * 4 + (threadIdx.x >> 6);
    const float v0 = s[(size_t)i * 128 + lane], v1 = s[(size_t)i * 128 + 64 + lane];
    float p[6];
#pragma unroll
    for (int m = 0; m < 6; ++m) p[m] = v0 * fw[m * 128 + lane] + v1 * fw[m * 128 + 64 + lane];
#pragma unroll
    for (int off = 32; off > 0; off >>= 1) {
#pragma unroll
        for (int m = 0; m < 6; ++m) p[m] += __shfl_down(p[m], off);
    }
    if (lane == 0) {
#pragma unroll
        for (int m = 0; m < 6; ++m) out[(size_t)i * 6 + m] = p[m] + fb[m];
    }
}

extern "C" void kernel_launch(void* const* d_in, const int* in_sizes, int n_in,
                              void* d_out, int out_size, void* d_ws, size_t ws_size,
                              hipStream_t stream) {
    const float* x = (const float*)d_in[0];
    const float* wih0 = (const float*)d_in[1];
    const float* whh0 = (const float*)d_in[2];
    const float* bih0 = (const float*)d_in[3];
    const float* bhh0 = (const float*)d_in[4];
    const float* wih1 = (const float*)d_in[5];
    const float* whh1 = (const float*)d_in[6];
    const float* bih1 = (const float*)d_in[7];
    const float* bhh1 = (const float*)d_in[8];
    const float* g1w = (const float*)d_in[9];
    const float* g1as = (const float*)d_in[10];
    const float* g1ad = (const float*)d_in[11];
    const float* g1b = (const float*)d_in[12];
    const float* g2w = (const float*)d_in[13];
    const float* g2as = (const float*)d_in[14];
    const float* g2ad = (const float*)d_in[15];
    const float* g2b = (const float*)d_in[16];
    const float* fcw = (const float*)d_in[17];
    const float* fcb = (const float*)d_in[18];
    const int* eidx = (const int*)d_in[19];
    const int* edge0 = eidx;
    const int* edge1 = eidx + E_EDGES;

    char* ws = (char*)d_ws;
    float* H0 = (float*)ws;                               // 40000*128 f32
    float* H1 = (float*)(ws + 20480000);                  // 40000*128 f32
    float* WH = (float*)(ws + 40960000);                  // 40000*512 f32
    float* AS = (float*)(ws + 122880000);                 // 40000*4 f32
    float* AD = (float*)(ws + 123520000);                 // 40000*4 f32
    float* WT = (float*)(ws + 124160000);                 // 151296 f32
    int* OFFS = (int*)(ws + 124765184);                   // 40001 int
    int* CURS = (int*)(ws + 124925248);                   // 40000 int (also cnt)
    int* ESORT = (int*)(ws + 125085248);                  // 680000 int

    hipMemsetAsync(CURS, 0, BN_TOTAL * sizeof(int), stream);
    transpose_w<<<591, 256, 0, stream>>>(wih0, whh0, wih1, whh1, WT);
    csr_count<<<(NE + 255) / 256, 256, 0, stream>>>(edge1, CURS);
    csr_scan<<<1, 1024, 0, stream>>>(CURS, OFFS, CURS);
    csr_fill<<<(NE + 255) / 256, 256, 0, stream>>>(edge1, CURS, ESORT);

    gru_kernel<<<1250, 256, 0, stream>>>(x, WT, bih0, bhh0, bih1, bhh1, H0);

    dim3 gg(625, 8);
    gat_gemm<<<gg, 256, 0, stream>>>(H0, g1w, WH);
    gat_alpha<<<10000, 256, 0, stream>>>(WH, g1as, g1ad, AS, AD);
    gat_aggregate<<<10000, 256, 0, stream>>>(WH, AS, AD, OFFS, ESORT, edge0, g1b, H1);

    gat_gemm<<<gg, 256, 0, stream>>>(H1, g2w, WH);
    gat_alpha<<<10000, 256, 0, stream>>>(WH, g2as, g2ad, AS, AD);
    gat_aggregate<<<10000, 256, 0, stream>>>(WH, AS, AD, OFFS, ESORT, edge0, g2b, H0);

    fc_kernel<<<10000, 256, 0, stream>>>(H0, fcw, fcb, (float*)d_out);
}

// Round 3
// 3178.865 us; speedup vs baseline: 1.9741x; 1.9741x over previous
//
#include <hip/hip_runtime.h>
#include <math.h>

#define T_STEPS 24
#define F_IN 10
#define HDIM 128
#define E_EDGES 80000
#define B_BATCH 8
#define N_NODES 5000
#define BN_TOTAL 40000
#define BE 640000
#define NE 680000
#define G3 384

typedef __attribute__((ext_vector_type(8))) short s16x8;
typedef __attribute__((ext_vector_type(4))) short s16x4;
typedef __attribute__((ext_vector_type(4))) float fx4;

__device__ __forceinline__ float sigmoidf_(float v) { return 1.f / (1.f + __expf(-v)); }
__device__ __forceinline__ float tanhf_(float v) { float e = __expf(2.f * v); return 1.f - 2.f / (e + 1.f); }

__device__ __forceinline__ short f2b(float f) {
    unsigned u = __float_as_uint(f);
    unsigned r = (u + 0x7fffu + ((u >> 16) & 1u)) >> 16;
    return (short)r;
}

// ---------------- pack weights into MFMA A-fragment order (bf16) ----------------
// pk layout (shorts): [0,49152) hh0 ; [49152,98304) ih1 ; [98304,147456) hh1 ; [147456,159744) ih0 (K padded 10->32)
// K=128 mats: pk[((nf*4+kf)*64+lane)*8+j] = W[nf*16+(lane&15)][kf*32+(lane>>4)*8+j]
__global__ void pack_w(const float* __restrict__ wih0, const float* __restrict__ whh0,
                       const float* __restrict__ wih1, const float* __restrict__ whh1,
                       short* __restrict__ pk) {
    int id = blockIdx.x * 256 + threadIdx.x;
    if (id < 147456) {
        int mat = id / 49152, r = id % 49152;
        int nf = r / 2048, r2 = r % 2048, kf = r2 / 512, r3 = r2 % 512, lane = r3 / 8, j = r3 % 8;
        int n = nf * 16 + (lane & 15), k = kf * 32 + (lane >> 4) * 8 + j;
        const float* src = (mat == 0) ? whh0 : (mat == 1) ? wih1 : whh1;
        pk[id] = f2b(src[n * 128 + k]);
    } else {
        int r = id - 147456;
        int nf = r / 512, r2 = r % 512, lane = r2 / 8, j = r2 % 8;
        int n = nf * 16 + (lane & 15), k = (lane >> 4) * 8 + j;
        pk[id] = (k < F_IN) ? f2b(wih0[n * F_IN + k]) : (short)0;
    }
}

// K=128 matmul: acc[part][jf][mf] += Wpack(A) x hLDS(B). parts: 0=r,1=z,g==2 -> P2 (2=nh,3=ni)
template<int P2>
__device__ __forceinline__ void mm128(const short* __restrict__ pkm, const short* __restrict__ hb,
                                      int w, int l, fx4 acc[4][2][4]) {
    const int lm = l & 15, lk = l >> 4;
#pragma unroll
    for (int kf = 0; kf < 4; ++kf) {
        s16x8 bfr[4];
#pragma unroll
        for (int mf = 0; mf < 4; ++mf) {
            const int m = mf * 16 + lm;
            const int slot = (kf * 4 + lk) ^ (m & 7);
            bfr[mf] = *(const s16x8*)&hb[m * 128 + slot * 8];
        }
#pragma unroll
        for (int g = 0; g < 3; ++g) {
            const int part = (g == 2) ? P2 : g;
#pragma unroll
            for (int jf = 0; jf < 2; ++jf) {
                const int nf = g * 8 + w * 2 + jf;
                const s16x8 af = *(const s16x8*)&pkm[((nf * 4 + kf) * 64 + l) * 8];
#pragma unroll
                for (int mf = 0; mf < 4; ++mf)
                    acc[part][jf][mf] = __builtin_amdgcn_mfma_f32_16x16x32_bf16(af, bfr[mf], acc[part][jf][mf], 0, 0, 0);
            }
        }
    }
}

// ---------------- fused 2-layer GRU via MFMA; 64 seqs/block, fp32 state in regs ----------------
__global__ __launch_bounds__(256, 2) void gru_mfma(
    const float* __restrict__ x, const short* __restrict__ pk,
    const float* __restrict__ bih0, const float* __restrict__ bhh0,
    const float* __restrict__ bih1, const float* __restrict__ bhh1,
    float* __restrict__ temporal) {
    __shared__ __align__(16) short h1b[64 * 128];
    __shared__ __align__(16) short h2b[64 * 128];
    __shared__ __align__(16) float blds[2][4][128];
    const int tid = threadIdx.x;
    const int w = tid >> 6, l = tid & 63;
    const int lm = l & 15, lk = l >> 4;
    const long sb = (long)blockIdx.x * 64;

    if (tid < 128) {
        const int j = tid;
        blds[0][0][j] = bih0[j] + bhh0[j];
        blds[0][1][j] = bih0[128 + j] + bhh0[128 + j];
        blds[0][2][j] = bhh0[256 + j];
        blds[0][3][j] = bih0[256 + j];
    } else {
        const int j = tid - 128;
        blds[1][0][j] = bih1[j] + bhh1[j];
        blds[1][1][j] = bih1[128 + j] + bhh1[128 + j];
        blds[1][2][j] = bhh1[256 + j];
        blds[1][3][j] = bih1[256 + j];
    }
    for (int i = tid; i < 64 * 128; i += 256) { h1b[i] = 0; h2b[i] = 0; }

    fx4 h1s[2][4], h2s[2][4];
#pragma unroll
    for (int jf = 0; jf < 2; ++jf)
#pragma unroll
        for (int mf = 0; mf < 4; ++mf) { h1s[jf][mf] = (fx4)(0.f); h2s[jf][mf] = (fx4)(0.f); }

    const short* pk_hh0 = pk;
    const short* pk_ih1 = pk + 49152;
    const short* pk_hh1 = pk + 98304;
    const short* pk_ih0 = pk + 147456;
    const int jb = w * 32 + lk * 4;

    __syncthreads();

    for (int tt = 0; tt < T_STEPS; ++tt) {
        fx4 acc[4][2][4];
        // --- x fragments (issue loads early; B-operand of ih0) ---
        s16x8 xfr[4];
#pragma unroll
        for (int mf = 0; mf < 4; ++mf) {
            const float* xr = x + (sb + mf * 16 + lm) * (T_STEPS * F_IN) + tt * F_IN;
            short v[8];
#pragma unroll
            for (int j = 0; j < 8; ++j) {
                const int k = lk * 8 + j;
                v[j] = (k < F_IN) ? f2b(xr[k]) : (short)0;
            }
            s16x8 t8 = { v[0], v[1], v[2], v[3], v[4], v[5], v[6], v[7] };
            xfr[mf] = t8;
        }
        // --- layer 0: init acc with biases, hh0 + ih0 matmuls ---
#pragma unroll
        for (int p = 0; p < 4; ++p)
#pragma unroll
            for (int jf = 0; jf < 2; ++jf) {
                const fx4 bv = *(const fx4*)&blds[0][p][jb + jf * 16];
#pragma unroll
                for (int mf = 0; mf < 4; ++mf) acc[p][jf][mf] = bv;
            }
        mm128<2>(pk_hh0, h1b, w, l, acc);
#pragma unroll
        for (int g = 0; g < 3; ++g) {
            const int part = (g == 2) ? 3 : g;
#pragma unroll
            for (int jf = 0; jf < 2; ++jf) {
                const int nf = g * 8 + w * 2 + jf;
                const s16x8 af = *(const s16x8*)&pk_ih0[(nf * 64 + l) * 8];
#pragma unroll
                for (int mf = 0; mf < 4; ++mf)
                    acc[part][jf][mf] = __builtin_amdgcn_mfma_f32_16x16x32_bf16(af, xfr[mf], acc[part][jf][mf], 0, 0, 0);
            }
        }
        // --- elementwise layer 0 -> h1 new (regs; defer LDS write) ---
        s16x4 w1[2][4];
#pragma unroll
        for (int jf = 0; jf < 2; ++jf)
#pragma unroll
            for (int mf = 0; mf < 4; ++mf) {
#pragma unroll
                for (int rg = 0; rg < 4; ++rg) {
                    const float r = sigmoidf_(acc[0][jf][mf][rg]);
                    const float z = sigmoidf_(acc[1][jf][mf][rg]);
                    const float n = tanhf_(acc[3][jf][mf][rg] + r * acc[2][jf][mf][rg]);
                    h1s[jf][mf][rg] = (1.f - z) * n + z * h1s[jf][mf][rg];
                }
                s16x4 p4 = { f2b(h1s[jf][mf][0]), f2b(h1s[jf][mf][1]), f2b(h1s[jf][mf][2]), f2b(h1s[jf][mf][3]) };
                w1[jf][mf] = p4;
            }
        // --- layer 1: init biases, hh1 (reads h2 old) ---
#pragma unroll
        for (int p = 0; p < 4; ++p)
#pragma unroll
            for (int jf = 0; jf < 2; ++jf) {
                const fx4 bv = *(const fx4*)&blds[1][p][jb + jf * 16];
#pragma unroll
                for (int mf = 0; mf < 4; ++mf) acc[p][jf][mf] = bv;
            }
        mm128<2>(pk_hh1, h2b, w, l, acc);
        __syncthreads();   // all reads of h1(old)/h2(old) complete
#pragma unroll
        for (int jf = 0; jf < 2; ++jf)
#pragma unroll
            for (int mf = 0; mf < 4; ++mf) {
                const int m = mf * 16 + lm;
                const int jj0 = jb + jf * 16;
                const int slot = (jj0 >> 3) ^ (m & 7);
                *(s16x4*)&h1b[m * 128 + slot * 8 + (jj0 & 7)] = w1[jf][mf];
            }
        __syncthreads();   // h1 new visible
        mm128<3>(pk_ih1, h1b, w, l, acc);
        // --- elementwise layer 1 -> h2 ---
#pragma unroll
        for (int jf = 0; jf < 2; ++jf)
#pragma unroll
            for (int mf = 0; mf < 4; ++mf) {
#pragma unroll
                for (int rg = 0; rg < 4; ++rg) {
                    const float r = sigmoidf_(acc[0][jf][mf][rg]);
                    const float z = sigmoidf_(acc[1][jf][mf][rg]);
                    const float n = tanhf_(acc[3][jf][mf][rg] + r * acc[2][jf][mf][rg]);
                    h2s[jf][mf][rg] = (1.f - z) * n + z * h2s[jf][mf][rg];
                }
                const int m = mf * 16 + lm;
                const int jj0 = jb + jf * 16;
                const int slot = (jj0 >> 3) ^ (m & 7);
                s16x4 p4 = { f2b(h2s[jf][mf][0]), f2b(h2s[jf][mf][1]), f2b(h2s[jf][mf][2]), f2b(h2s[jf][mf][3]) };
                *(s16x4*)&h2b[m * 128 + slot * 8 + (jj0 & 7)] = p4;
            }
        __syncthreads();   // h2 new visible for next step
    }
#pragma unroll
    for (int jf = 0; jf < 2; ++jf)
#pragma unroll
        for (int mf = 0; mf < 4; ++mf) {
            const long m = sb + mf * 16 + lm;
            const int jj0 = jb + jf * 16;
            *(fx4*)&temporal[m * 128 + jj0] = h2s[jf][mf];
        }
}

// ---------------- CSR build ----------------
__global__ void csr_count(const int* __restrict__ edge1, int* __restrict__ cnt) {
    int e = blockIdx.x * 256 + threadIdx.x;
    if (e >= NE) return;
    int d;
    if (e < BE) { int b = e / E_EDGES; d = edge1[e - b * E_EDGES] + b * N_NODES; }
    else d = e - BE;
    atomicAdd(&cnt[d], 1);
}

__global__ void csr_scan(const int* cnt, int* offs, int* curs) {
    __shared__ int part[1024];
    const int t = threadIdx.x;
    const int base = t * 40;
    int end = base + 40; if (end > BN_TOTAL) end = BN_TOTAL;
    int s = 0;
    for (int i = base; i < end; ++i) s += cnt[i];
    part[t] = s;
    __syncthreads();
    for (int off = 1; off < 1024; off <<= 1) {
        int v = (t >= off) ? part[t - off] : 0;
        __syncthreads();
        part[t] += v;
        __syncthreads();
    }
    int run = part[t] - s;
    for (int i = base; i < end; ++i) {
        int c = cnt[i];
        offs[i] = run; curs[i] = run; run += c;
    }
    if (t == 1023) offs[BN_TOTAL] = NE;
}

__global__ void csr_fill(const int* __restrict__ edge1, int* __restrict__ curs, int* __restrict__ esort) {
    int e = blockIdx.x * 256 + threadIdx.x;
    if (e >= NE) return;
    int d;
    if (e < BE) { int b = e / E_EDGES; d = edge1[e - b * E_EDGES] + b * N_NODES; }
    else d = e - BE;
    int pos = atomicAdd(&curs[d], 1);
    esort[pos] = e;
}

// ---------------- GAT: wh = feat @ W.T  (tiled 64x64, K=128) ----------------
__global__ __launch_bounds__(256) void gat_gemm(const float* __restrict__ feat,
                                                const float* __restrict__ W,
                                                float* __restrict__ wh) {
    __shared__ float As[64][129];
    __shared__ float Bs[64][129];
    const int t = threadIdx.x;
    const int i0 = blockIdx.x * 64;
    const int j0 = blockIdx.y * 64;
    for (int idx = t; idx < 64 * 128; idx += 256) {
        int r = idx >> 7, c = idx & 127;
        As[r][c] = feat[(size_t)(i0 + r) * 128 + c];
        Bs[r][c] = W[(size_t)(j0 + r) * 128 + c];
    }
    __syncthreads();
    const int tr = (t >> 4) * 4;
    const int tc = (t & 15) * 4;
    float acc[4][4] = {};
    for (int k = 0; k < 128; ++k) {
        float a[4], b[4];
#pragma unroll
        for (int q = 0; q < 4; ++q) { a[q] = As[tr + q][k]; b[q] = Bs[tc + q][k]; }
#pragma unroll
        for (int i = 0; i < 4; ++i)
#pragma unroll
            for (int j = 0; j < 4; ++j) acc[i][j] += a[i] * b[j];
    }
#pragma unroll
    for (int i = 0; i < 4; ++i)
#pragma unroll
        for (int j = 0; j < 4; ++j)
            wh[(size_t)(i0 + tr + i) * 512 + j0 + tc + j] = acc[i][j];
}

// ---------------- per-node alpha_src / alpha_dst ----------------
__global__ __launch_bounds__(256) void gat_alpha(const float* __restrict__ wh,
                                                 const float* __restrict__ asrc, const float* __restrict__ adst,
                                                 float* __restrict__ AS, float* __restrict__ AD) {
    const int lane = threadIdx.x & 63;
    const int node = blockIdx.x * 4 + (threadIdx.x >> 6);
    const float* r = wh + (size_t)node * 512;
    float ps[4], pd[4];
#pragma unroll
    for (int hd = 0; hd < 4; ++hd) {
        float w0 = r[hd * 128 + lane], w1 = r[hd * 128 + 64 + lane];
        ps[hd] = w0 * asrc[hd * 128 + lane] + w1 * asrc[hd * 128 + 64 + lane];
        pd[hd] = w0 * adst[hd * 128 + lane] + w1 * adst[hd * 128 + 64 + lane];
    }
#pragma unroll
    for (int off = 32; off > 0; off >>= 1) {
#pragma unroll
        for (int hd = 0; hd < 4; ++hd) {
            ps[hd] += __shfl_down(ps[hd], off);
            pd[hd] += __shfl_down(pd[hd], off);
        }
    }
    if (lane == 0) {
#pragma unroll
        for (int hd = 0; hd < 4; ++hd) { AS[node * 4 + hd] = ps[hd]; AD[node * 4 + hd] = pd[hd]; }
    }
}

__device__ __forceinline__ int decode_src(int eid, const int* __restrict__ edge0) {
    if (eid < BE) { int b = eid / E_EDGES; return edge0[eid - b * E_EDGES] + b * N_NODES; }
    return eid - BE;
}

// ---------------- per-node softmax attention + aggregate (one wave / node) ----------------
__global__ __launch_bounds__(256) void gat_aggregate(const float* __restrict__ wh,
                                                     const float* __restrict__ AS, const float* __restrict__ AD,
                                                     const int* __restrict__ offs, const int* __restrict__ esort,
                                                     const int* __restrict__ edge0, const float* __restrict__ bias,
                                                     float* __restrict__ outf) {
    const int lane = threadIdx.x & 63;
    const int d = blockIdx.x * 4 + (threadIdx.x >> 6);
    const int e0 = offs[d], e1 = offs[d + 1];
    const float ad0 = AD[d * 4 + 0], ad1 = AD[d * 4 + 1], ad2 = AD[d * 4 + 2], ad3 = AD[d * 4 + 3];
    float mx0 = -1e30f, mx1 = -1e30f, mx2 = -1e30f, mx3 = -1e30f;
    for (int e = e0; e < e1; ++e) {
        const int src = decode_src(esort[e], edge0);
        float v0 = AS[src * 4 + 0] + ad0; v0 = v0 > 0.f ? v0 : 0.2f * v0; mx0 = fmaxf(mx0, v0);
        float v1 = AS[src * 4 + 1] + ad1; v1 = v1 > 0.f ? v1 : 0.2f * v1; mx1 = fmaxf(mx1, v1);
        float v2 = AS[src * 4 + 2] + ad2; v2 = v2 > 0.f ? v2 : 0.2f * v2; mx2 = fmaxf(mx2, v2);
        float v3 = AS[src * 4 + 3] + ad3; v3 = v3 > 0.f ? v3 : 0.2f * v3; mx3 = fmaxf(mx3, v3);
    }
    float den0 = 0.f, den1 = 0.f, den2 = 0.f, den3 = 0.f;
    float acc[8] = {0.f, 0.f, 0.f, 0.f, 0.f, 0.f, 0.f, 0.f};
    for (int e = e0; e < e1; ++e) {
        const int src = decode_src(esort[e], edge0);
        float v0 = AS[src * 4 + 0] + ad0; v0 = v0 > 0.f ? v0 : 0.2f * v0; float ex0 = __expf(v0 - mx0); den0 += ex0;
        float v1 = AS[src * 4 + 1] + ad1; v1 = v1 > 0.f ? v1 : 0.2f * v1; float ex1 = __expf(v1 - mx1); den1 += ex1;
        float v2 = AS[src * 4 + 2] + ad2; v2 = v2 > 0.f ? v2 : 0.2f * v2; float ex2 = __expf(v2 - mx2); den2 += ex2;
        float v3 = AS[src * 4 + 3] + ad3; v3 = v3 > 0.f ? v3 : 0.2f * v3; float ex3 = __expf(v3 - mx3); den3 += ex3;
        const float* wr = wh + (size_t)src * 512;
        acc[0] += ex0 * wr[lane];        acc[1] += ex0 * wr[64 + lane];
        acc[2] += ex1 * wr[128 + lane];  acc[3] += ex1 * wr[192 + lane];
        acc[4] += ex2 * wr[256 + lane];  acc[5] += ex2 * wr[320 + lane];
        acc[6] += ex3 * wr[384 + lane];  acc[7] += ex3 * wr[448 + lane];
    }
    den0 += 1e-16f; den1 += 1e-16f; den2 += 1e-16f; den3 += 1e-16f;
    const float o0 = 0.25f * (acc[0] / den0 + acc[2] / den1 + acc[4] / den2 + acc[6] / den3) + bias[lane];
    const float o1 = 0.25f * (acc[1] / den0 + acc[3] / den1 + acc[5] / den2 + acc[7] / den3) + bias[64 + lane];
    outf[(size_t)d * 128 + lane] = fmaxf(o0, 0.f);
    outf[(size_t)d * 128 + 64 + lane] = fmaxf(o1, 0.f);
}

// ---------------- final FC: one wave / node ----------------
__global__ __launch_bounds__(256) void fc_kernel(const float* __restrict__ s,
                                                 const float* __restrict__ fw, const float* __restrict__ fb,
                                                 float* __restrict__ out) {
    const int lane = threadIdx.x & 63;
    const int i = blockIdx.x * 4 + (threadIdx.x >> 6);
    const float v0 = s[(size_t)i * 128 + lane], v1 = s[(size_t)i * 128 + 64 + lane];
    float p[6];
#pragma unroll
    for (int m = 0; m < 6; ++m) p[m] = v0 * fw[m * 128 + lane] + v1 * fw[m * 128 + 64 + lane];
#pragma unroll
    for (int off = 32; off > 0; off >>= 1) {
#pragma unroll
        for (int m = 0; m < 6; ++m) p[m] += __shfl_down(p[m], off);
    }
    if (lane == 0) {
#pragma unroll
        for (int m = 0; m < 6; ++m) out[(size_t)i * 6 + m] = p[m] + fb[m];
    }
}

extern "C" void kernel_launch(void* const* d_in, const int* in_sizes, int n_in,
                              void* d_out, int out_size, void* d_ws, size_t ws_size,
                              hipStream_t stream) {
    const float* x = (const float*)d_in[0];
    const float* wih0 = (const float*)d_in[1];
    const float* whh0 = (const float*)d_in[2];
    const float* bih0 = (const float*)d_in[3];
    const float* bhh0 = (const float*)d_in[4];
    const float* wih1 = (const float*)d_in[5];
    const float* whh1 = (const float*)d_in[6];
    const float* bih1 = (const float*)d_in[7];
    const float* bhh1 = (const float*)d_in[8];
    const float* g1w = (const float*)d_in[9];
    const float* g1as = (const float*)d_in[10];
    const float* g1ad = (const float*)d_in[11];
    const float* g1b = (const float*)d_in[12];
    const float* g2w = (const float*)d_in[13];
    const float* g2as = (const float*)d_in[14];
    const float* g2ad = (const float*)d_in[15];
    const float* g2b = (const float*)d_in[16];
    const float* fcw = (const float*)d_in[17];
    const float* fcb = (const float*)d_in[18];
    const int* eidx = (const int*)d_in[19];
    const int* edge0 = eidx;
    const int* edge1 = eidx + E_EDGES;

    char* ws = (char*)d_ws;
    float* H0 = (float*)ws;                               // 40000*128 f32
    float* H1 = (float*)(ws + 20480000);                  // 40000*128 f32
    float* WH = (float*)(ws + 40960000);                  // 40000*512 f32
    float* AS = (float*)(ws + 122880000);                 // 40000*4 f32
    float* AD = (float*)(ws + 123520000);                 // 40000*4 f32
    short* PK = (short*)(ws + 124160000);                 // 159744 bf16 (packed weights)
    int* OFFS = (int*)(ws + 124765184);                   // 40001 int
    int* CURS = (int*)(ws + 124925248);                   // 40000 int (also cnt)
    int* ESORT = (int*)(ws + 125085248);                  // 680000 int

    hipMemsetAsync(CURS, 0, BN_TOTAL * sizeof(int), stream);
    pack_w<<<624, 256, 0, stream>>>(wih0, whh0, wih1, whh1, PK);
    csr_count<<<(NE + 255) / 256, 256, 0, stream>>>(edge1, CURS);
    csr_scan<<<1, 1024, 0, stream>>>(CURS, OFFS, CURS);
    csr_fill<<<(NE + 255) / 256, 256, 0, stream>>>(edge1, CURS, ESORT);

    gru_mfma<<<625, 256, 0, stream>>>(x, PK, bih0, bhh0, bih1, bhh1, H0);

    dim3 gg(625, 8);
    gat_gemm<<<gg, 256, 0, stream>>>(H0, g1w, WH);
    gat_alpha<<<10000, 256, 0, stream>>>(WH, g1as, g1ad, AS, AD);
    gat_aggregate<<<10000, 256, 0, stream>>>(WH, AS, AD, OFFS, ESORT, edge0, g1b, H1);

    gat_gemm<<<gg, 256, 0, stream>>>(H1, g2w, WH);
    gat_alpha<<<10000, 256, 0, stream>>>(WH, g2as, g2ad, AS, AD);
    gat_aggregate<<<10000, 256, 0, stream>>>(WH, AS, AD, OFFS, ESORT, edge0, g2b, H0);

    fc_kernel<<<10000, 256, 0, stream>>>(H0, fcw, fcb, (float*)d_out);
}

// Round 4
// 2570.666 us; speedup vs baseline: 2.4411x; 1.2366x over previous
//
#include <hip/hip_runtime.h>
#include <math.h>

#define T_STEPS 24
#define F_IN 10
#define HDIM 128
#define E_EDGES 80000
#define B_BATCH 8
#define N_NODES 5000
#define BN_TOTAL 40000
#define BE 640000
#define NE 680000
#define G3 384
#define SEQ_BLK 128
#define GRU_BLOCKS 313   // 312*128 + 64

typedef __attribute__((ext_vector_type(8))) short s16x8;
typedef __attribute__((ext_vector_type(4))) short s16x4;
typedef __attribute__((ext_vector_type(4))) float fx4;
typedef __attribute__((ext_vector_type(2))) float fx2;

__device__ __forceinline__ float sigmoidf_(float v) { return 1.f / (1.f + __expf(-v)); }
__device__ __forceinline__ float tanhf_(float v) { float e = __expf(2.f * v); return 1.f - 2.f / (e + 1.f); }

__device__ __forceinline__ short f2b(float f) {
    unsigned u = __float_as_uint(f);
    unsigned r = (u + 0x7fffu + ((u >> 16) & 1u)) >> 16;
    return (short)r;
}

// ---------------- pack weights, slice-contiguous for LDS staging ----------------
// shorts: [0,49152) hh0 ; [49152,98304) hh1 ; [98304,147456) ih1 ; [147456,159744) ih0
// K=128 mats: pk[mat][kf][nf][lane][j] = W[nf*16+(lane&15)][kf*32+(lane>>4)*8+j]
// each (mat,kf) slice = 24*64*8 shorts = 24576 B contiguous.
__global__ void pack_w(const float* __restrict__ wih0, const float* __restrict__ whh0,
                       const float* __restrict__ wih1, const float* __restrict__ whh1,
                       short* __restrict__ pk) {
    int id = blockIdx.x * 256 + threadIdx.x;
    if (id < 147456) {
        int mat = id / 49152, r = id % 49152;
        int kf = r / 12288, r2 = r % 12288, nf = r2 / 512, r3 = r2 % 512, lane = r3 / 8, j = r3 % 8;
        int n = nf * 16 + (lane & 15), k = kf * 32 + (lane >> 4) * 8 + j;
        const float* src = (mat == 0) ? whh0 : (mat == 1) ? whh1 : wih1;
        pk[id] = f2b(src[n * 128 + k]);
    } else {
        int r = id - 147456;
        int nf = r / 512, r2 = r % 512, lane = r2 / 8, j = r2 % 8;
        int n = nf * 16 + (lane & 15), k = (lane >> 4) * 8 + j;
        pk[id] = (k < F_IN) ? f2b(wih0[n * F_IN + k]) : (short)0;
    }
}

// ---- async 24 KB slice stage: 512 threads x 3 x 16B, wave-uniform LDS dest ----
__device__ __forceinline__ void stage24(const short* gsrc, short* ldst, int w8, int l) {
#pragma unroll
    for (int r = 0; r < 3; ++r) {
        const int off = r * 8192 + w8 * 1024;
        __builtin_amdgcn_global_load_lds(
            (const __attribute__((address_space(1))) unsigned int*)((const char*)gsrc + off + l * 16),
            (__attribute__((address_space(3))) unsigned int*)((char*)ldst + off),
            16, 0, 0);
    }
}

// one kf-slice matmul: 24 MFMA, A from wslab, B from h LDS (XOR-swizzled)
template<int P2>
__device__ __forceinline__ void mm_slice(const short* __restrict__ slab, const short* __restrict__ hb,
                                         const int kf, const int c, const int sh, const int l,
                                         fx4 acc[4][2][4]) {
    const int lm = l & 15, lk = l >> 4;
    s16x8 bfr[4];
#pragma unroll
    for (int mf = 0; mf < 4; ++mf) {
        const int m = sh * 64 + mf * 16 + lm;
        const int slot = (kf * 4 + lk) ^ (m & 7);
        bfr[mf] = *(const s16x8*)&hb[m * 128 + slot * 8];
    }
#pragma unroll
    for (int g = 0; g < 3; ++g) {
        const int part = (g == 2) ? P2 : g;
#pragma unroll
        for (int jf = 0; jf < 2; ++jf) {
            const int nf = g * 8 + c * 2 + jf;
            const s16x8 af = *(const s16x8*)&slab[(nf * 64 + l) * 8];
#pragma unroll
            for (int mf = 0; mf < 4; ++mf)
                acc[part][jf][mf] = __builtin_amdgcn_mfma_f32_16x16x32_bf16(af, bfr[mf], acc[part][jf][mf], 0, 0, 0);
        }
    }
}

#define VMW3 asm volatile("s_waitcnt vmcnt(3)" ::: "memory")
#define VMW0 asm volatile("s_waitcnt vmcnt(0)" ::: "memory")
#define LGW0 asm volatile("s_waitcnt lgkmcnt(0)" ::: "memory")
#define FEN  asm volatile("" ::: "memory")
#define HBAR __builtin_amdgcn_s_barrier()

// barA: my stage(s) done (counted, stage(s+1) stays in flight) -> slab readable
// barB: all waves' slab reads returned -> buffer may be re-staged
#define SLICE3(SOFF, SBUF, RBUF, HB, KF, PP)                 \
    stage24(pk + (SOFF), SBUF, w, l);                        \
    VMW3; HBAR; FEN;                                         \
    mm_slice<PP>(RBUF, HB, KF, c, sh, l, acc);               \
    LGW0; HBAR; FEN;

#define SLICEL(RBUF, HB, KF, PP)                             \
    VMW0; HBAR; FEN;                                         \
    mm_slice<PP>(RBUF, HB, KF, c, sh, l, acc);               \
    LGW0; HBAR; FEN;

// ---------------- fused 2-layer GRU; 128 seqs/block, LDS-staged weights ----------------
__global__ __launch_bounds__(512, 1) void gru_mfma(
    const float* __restrict__ x, const short* __restrict__ pk,
    const float* __restrict__ bih0, const float* __restrict__ bhh0,
    const float* __restrict__ bih1, const float* __restrict__ bhh1,
    float* __restrict__ temporal) {
    __shared__ __align__(16) short h1b[128 * 128];
    __shared__ __align__(16) short h2b[128 * 128];
    __shared__ __align__(16) short wslab[2][12288];
    __shared__ __align__(16) short ih0s[12288];
    __shared__ __align__(16) float blds[2][4][128];
    const int tid = threadIdx.x;
    const int w = tid >> 6, l = tid & 63;
    const int c = w & 3;        // column group (32 cols)
    const int sh = w >> 2;      // sequence half (64 rows)
    const int lm = l & 15, lk = l >> 4;
    const int jb = c * 32 + lk * 4;
    const long sb = (long)blockIdx.x * SEQ_BLK;
    short* wsl0 = wslab[0];
    short* wsl1 = wslab[1];

    if (tid < 128) {
        const int j = tid;
        blds[0][0][j] = bih0[j] + bhh0[j];
        blds[0][1][j] = bih0[128 + j] + bhh0[128 + j];
        blds[0][2][j] = bhh0[256 + j];
        blds[0][3][j] = bih0[256 + j];
    } else if (tid < 256) {
        const int j = tid - 128;
        blds[1][0][j] = bih1[j] + bhh1[j];
        blds[1][1][j] = bih1[128 + j] + bhh1[128 + j];
        blds[1][2][j] = bhh1[256 + j];
        blds[1][3][j] = bih1[256 + j];
    }
    for (int i = tid; i < 128 * 128; i += 512) { h1b[i] = 0; h2b[i] = 0; }
    stage24(pk + 147456, ih0s, w, l);      // resident ih0
    VMW0;
    __syncthreads();

    fx4 h1s[2][4], h2s[2][4];
#pragma unroll
    for (int jf = 0; jf < 2; ++jf)
#pragma unroll
        for (int mf = 0; mf < 4; ++mf) { h1s[jf][mf] = (fx4)(0.f); h2s[jf][mf] = (fx4)(0.f); }

    for (int tt = 0; tt < T_STEPS; ++tt) {
        // --- x loads (issued before stages; older in vmcnt, drained by first VMW3) ---
        fx2 xa[4][4];
#pragma unroll
        for (int mf = 0; mf < 4; ++mf) {
            xa[mf][0] = (fx2)(0.f); xa[mf][1] = (fx2)(0.f); xa[mf][2] = (fx2)(0.f); xa[mf][3] = (fx2)(0.f);
            const long m = sb + sh * 64 + mf * 16 + lm;
            if (m < BN_TOTAL) {
                const float* xr = x + m * (T_STEPS * F_IN) + tt * F_IN;
                if (lk == 0) {
                    xa[mf][0] = *(const fx2*)(xr);     xa[mf][1] = *(const fx2*)(xr + 2);
                    xa[mf][2] = *(const fx2*)(xr + 4); xa[mf][3] = *(const fx2*)(xr + 6);
                } else if (lk == 1) {
                    xa[mf][0] = *(const fx2*)(xr + 8);
                }
            }
        }
        stage24(pk + 0, wsl0, w, l);       // hh0 kf0
        fx4 acc[4][2][4];
#pragma unroll
        for (int p = 0; p < 4; ++p)
#pragma unroll
            for (int jf = 0; jf < 2; ++jf) {
                const fx4 bv = *(const fx4*)&blds[0][p][jb + jf * 16];
#pragma unroll
                for (int mf = 0; mf < 4; ++mf) acc[p][jf][mf] = bv;
            }
        // ===== layer 0: hh0 (B = h1 old) =====
        SLICE3(12288, wsl1, wsl0, h1b, 0, 2);
        SLICE3(24576, wsl0, wsl1, h1b, 1, 2);
        SLICE3(36864, wsl1, wsl0, h1b, 2, 2);
        SLICE3(49152, wsl0, wsl1, h1b, 3, 2);    // stages hh1 kf0
        // --- ih0 (A resident LDS, B = x frags) -> parts r,z,ni ---
        s16x8 xfr[4];
#pragma unroll
        for (int mf = 0; mf < 4; ++mf) {
            s16x8 t = { f2b(xa[mf][0].x), f2b(xa[mf][0].y), f2b(xa[mf][1].x), f2b(xa[mf][1].y),
                        f2b(xa[mf][2].x), f2b(xa[mf][2].y), f2b(xa[mf][3].x), f2b(xa[mf][3].y) };
            xfr[mf] = t;
        }
#pragma unroll
        for (int g = 0; g < 3; ++g) {
            const int part = (g == 2) ? 3 : g;
#pragma unroll
            for (int jf = 0; jf < 2; ++jf) {
                const int nf = g * 8 + c * 2 + jf;
                const s16x8 af = *(const s16x8*)&ih0s[(nf * 64 + l) * 8];
#pragma unroll
                for (int mf = 0; mf < 4; ++mf)
                    acc[part][jf][mf] = __builtin_amdgcn_mfma_f32_16x16x32_bf16(af, xfr[mf], acc[part][jf][mf], 0, 0, 0);
            }
        }
        // --- elementwise layer 0 (overlaps hh1-kf0 stage in flight) ---
        s16x4 w1[2][4];
#pragma unroll
        for (int jf = 0; jf < 2; ++jf)
#pragma unroll
            for (int mf = 0; mf < 4; ++mf) {
#pragma unroll
                for (int rg = 0; rg < 4; ++rg) {
                    const float r = sigmoidf_(acc[0][jf][mf][rg]);
                    const float z = sigmoidf_(acc[1][jf][mf][rg]);
                    const float n = tanhf_(acc[3][jf][mf][rg] + r * acc[2][jf][mf][rg]);
                    h1s[jf][mf][rg] = (1.f - z) * n + z * h1s[jf][mf][rg];
                }
                s16x4 p4 = { f2b(h1s[jf][mf][0]), f2b(h1s[jf][mf][1]), f2b(h1s[jf][mf][2]), f2b(h1s[jf][mf][3]) };
                w1[jf][mf] = p4;
            }
        // re-init acc with layer-1 biases
#pragma unroll
        for (int p = 0; p < 4; ++p)
#pragma unroll
            for (int jf = 0; jf < 2; ++jf) {
                const fx4 bv = *(const fx4*)&blds[1][p][jb + jf * 16];
#pragma unroll
                for (int mf = 0; mf < 4; ++mf) acc[p][jf][mf] = bv;
            }
        // ===== layer 1: hh1 (B = h2 old) =====
        SLICE3(61440, wsl1, wsl0, h2b, 0, 2);
        SLICE3(73728, wsl0, wsl1, h2b, 1, 2);
        SLICE3(86016, wsl1, wsl0, h2b, 2, 2);
        SLICE3(98304, wsl0, wsl1, h2b, 3, 2);    // stages ih1 kf0
        // --- publish h1 new (h1b last read at slice 3; all waves barB'd since) ---
#pragma unroll
        for (int jf = 0; jf < 2; ++jf)
#pragma unroll
            for (int mf = 0; mf < 4; ++mf) {
                const int m = sh * 64 + mf * 16 + lm;
                const int jj0 = jb + jf * 16;
                const int slot = (jj0 >> 3) ^ (m & 7);
                *(s16x4*)&h1b[m * 128 + slot * 8 + (jj0 & 7)] = w1[jf][mf];
            }
        LGW0; HBAR; FEN;
        // ===== layer 1: ih1 (B = h1 new) =====
        SLICE3(110592, wsl1, wsl0, h1b, 0, 3);
        SLICE3(122880, wsl0, wsl1, h1b, 1, 3);
        SLICE3(135168, wsl1, wsl0, h1b, 2, 3);
        SLICEL(wsl1, h1b, 3, 3);
        // --- elementwise layer 1 -> h2, publish ---
#pragma unroll
        for (int jf = 0; jf < 2; ++jf)
#pragma unroll
            for (int mf = 0; mf < 4; ++mf) {
#pragma unroll
                for (int rg = 0; rg < 4; ++rg) {
                    const float r = sigmoidf_(acc[0][jf][mf][rg]);
                    const float z = sigmoidf_(acc[1][jf][mf][rg]);
                    const float n = tanhf_(acc[3][jf][mf][rg] + r * acc[2][jf][mf][rg]);
                    h2s[jf][mf][rg] = (1.f - z) * n + z * h2s[jf][mf][rg];
                }
                const int m = sh * 64 + mf * 16 + lm;
                const int jj0 = jb + jf * 16;
                const int slot = (jj0 >> 3) ^ (m & 7);
                s16x4 p4 = { f2b(h2s[jf][mf][0]), f2b(h2s[jf][mf][1]), f2b(h2s[jf][mf][2]), f2b(h2s[jf][mf][3]) };
                *(s16x4*)&h2b[m * 128 + slot * 8 + (jj0 & 7)] = p4;
            }
        LGW0; HBAR; FEN;
    }
#pragma unroll
    for (int jf = 0; jf < 2; ++jf)
#pragma unroll
        for (int mf = 0; mf < 4; ++mf) {
            const long m = sb + sh * 64 + mf * 16 + lm;
            if (m < BN_TOTAL)
                *(fx4*)&temporal[m * 128 + jb + jf * 16] = h2s[jf][mf];
        }
}

// ---------------- CSR build ----------------
__global__ void csr_count(const int* __restrict__ edge1, int* __restrict__ cnt) {
    int e = blockIdx.x * 256 + threadIdx.x;
    if (e >= NE) return;
    int d;
    if (e < BE) { int b = e / E_EDGES; d = edge1[e - b * E_EDGES] + b * N_NODES; }
    else d = e - BE;
    atomicAdd(&cnt[d], 1);
}

__global__ void csr_scan(const int* cnt, int* offs, int* curs) {
    __shared__ int part[1024];
    const int t = threadIdx.x;
    const int base = t * 40;
    int end = base + 40; if (end > BN_TOTAL) end = BN_TOTAL;
    int s = 0;
    for (int i = base; i < end; ++i) s += cnt[i];
    part[t] = s;
    __syncthreads();
    for (int off = 1; off < 1024; off <<= 1) {
        int v = (t >= off) ? part[t - off] : 0;
        __syncthreads();
        part[t] += v;
        __syncthreads();
    }
    int run = part[t] - s;
    for (int i = base; i < end; ++i) {
        int c = cnt[i];
        offs[i] = run; curs[i] = run; run += c;
    }
    if (t == 1023) offs[BN_TOTAL] = NE;
}

__global__ void csr_fill(const int* __restrict__ edge1, int* __restrict__ curs, int* __restrict__ esort) {
    int e = blockIdx.x * 256 + threadIdx.x;
    if (e >= NE) return;
    int d;
    if (e < BE) { int b = e / E_EDGES; d = edge1[e - b * E_EDGES] + b * N_NODES; }
    else d = e - BE;
    int pos = atomicAdd(&curs[d], 1);
    esort[pos] = e;
}

// ---------------- GAT: wh = feat @ W.T  (tiled 64x64, K=128) ----------------
__global__ __launch_bounds__(256) void gat_gemm(const float* __restrict__ feat,
                                                const float* __restrict__ W,
                                                float* __restrict__ wh) {
    __shared__ float As[64][129];
    __shared__ float Bs[64][129];
    const int t = threadIdx.x;
    const int i0 = blockIdx.x * 64;
    const int j0 = blockIdx.y * 64;
    for (int idx = t; idx < 64 * 128; idx += 256) {
        int r = idx >> 7, c = idx & 127;
        As[r][c] = feat[(size_t)(i0 + r) * 128 + c];
        Bs[r][c] = W[(size_t)(j0 + r) * 128 + c];
    }
    __syncthreads();
    const int tr = (t >> 4) * 4;
    const int tc = (t & 15) * 4;
    float acc[4][4] = {};
    for (int k = 0; k < 128; ++k) {
        float a[4], b[4];
#pragma unroll
        for (int q = 0; q < 4; ++q) { a[q] = As[tr + q][k]; b[q] = Bs[tc + q][k]; }
#pragma unroll
        for (int i = 0; i < 4; ++i)
#pragma unroll
            for (int j = 0; j < 4; ++j) acc[i][j] += a[i] * b[j];
    }
#pragma unroll
    for (int i = 0; i < 4; ++i)
#pragma unroll
        for (int j = 0; j < 4; ++j)
            wh[(size_t)(i0 + tr + i) * 512 + j0 + tc + j] = acc[i][j];
}

// ---------------- per-node alpha_src / alpha_dst ----------------
__global__ __launch_bounds__(256) void gat_alpha(const float* __restrict__ wh,
                                                 const float* __restrict__ asrc, const float* __restrict__ adst,
                                                 float* __restrict__ AS, float* __restrict__ AD) {
    const int lane = threadIdx.x & 63;
    const int node = blockIdx.x * 4 + (threadIdx.x >> 6);
    const float* r = wh + (size_t)node * 512;
    float ps[4], pd[4];
#pragma unroll
    for (int hd = 0; hd < 4; ++hd) {
        float w0 = r[hd * 128 + lane], w1 = r[hd * 128 + 64 + lane];
        ps[hd] = w0 * asrc[hd * 128 + lane] + w1 * asrc[hd * 128 + 64 + lane];
        pd[hd] = w0 * adst[hd * 128 + lane] + w1 * adst[hd * 128 + 64 + lane];
    }
#pragma unroll
    for (int off = 32; off > 0; off >>= 1) {
#pragma unroll
        for (int hd = 0; hd < 4; ++hd) {
            ps[hd] += __shfl_down(ps[hd], off);
            pd[hd] += __shfl_down(pd[hd], off);
        }
    }
    if (lane == 0) {
#pragma unroll
        for (int hd = 0; hd < 4; ++hd) { AS[node * 4 + hd] = ps[hd]; AD[node * 4 + hd] = pd[hd]; }
    }
}

__device__ __forceinline__ int decode_src(int eid, const int* __restrict__ edge0) {
    if (eid < BE) { int b = eid / E_EDGES; return edge0[eid - b * E_EDGES] + b * N_NODES; }
    return eid - BE;
}

// ---------------- per-node softmax attention + aggregate (one wave / node) ----------------
__global__ __launch_bounds__(256) void gat_aggregate(const float* __restrict__ wh,
                                                     const float* __restrict__ AS, const float* __restrict__ AD,
                                                     const int* __restrict__ offs, const int* __restrict__ esort,
                                                     const int* __restrict__ edge0, const float* __restrict__ bias,
                                                     float* __restrict__ outf) {
    const int lane = threadIdx.x & 63;
    const int d = blockIdx.x * 4 + (threadIdx.x >> 6);
    const int e0 = offs[d], e1 = offs[d + 1];
    const float ad0 = AD[d * 4 + 0], ad1 = AD[d * 4 + 1], ad2 = AD[d * 4 + 2], ad3 = AD[d * 4 + 3];
    float mx0 = -1e30f, mx1 = -1e30f, mx2 = -1e30f, mx3 = -1e30f;
    for (int e = e0; e < e1; ++e) {
        const int src = decode_src(esort[e], edge0);
        float v0 = AS[src * 4 + 0] + ad0; v0 = v0 > 0.f ? v0 : 0.2f * v0; mx0 = fmaxf(mx0, v0);
        float v1 = AS[src * 4 + 1] + ad1; v1 = v1 > 0.f ? v1 : 0.2f * v1; mx1 = fmaxf(mx1, v1);
        float v2 = AS[src * 4 + 2] + ad2; v2 = v2 > 0.f ? v2 : 0.2f * v2; mx2 = fmaxf(mx2, v2);
        float v3 = AS[src * 4 + 3] + ad3; v3 = v3 > 0.f ? v3 : 0.2f * v3; mx3 = fmaxf(mx3, v3);
    }
    float den0 = 0.f, den1 = 0.f, den2 = 0.f, den3 = 0.f;
    float acc[8] = {0.f, 0.f, 0.f, 0.f, 0.f, 0.f, 0.f, 0.f};
    for (int e = e0; e < e1; ++e) {
        const int src = decode_src(esort[e], edge0);
        float v0 = AS[src * 4 + 0] + ad0; v0 = v0 > 0.f ? v0 : 0.2f * v0; float ex0 = __expf(v0 - mx0); den0 += ex0;
        float v1 = AS[src * 4 + 1] + ad1; v1 = v1 > 0.f ? v1 : 0.2f * v1; float ex1 = __expf(v1 - mx1); den1 += ex1;
        float v2 = AS[src * 4 + 2] + ad2; v2 = v2 > 0.f ? v2 : 0.2f * v2; float ex2 = __expf(v2 - mx2); den2 += ex2;
        float v3 = AS[src * 4 + 3] + ad3; v3 = v3 > 0.f ? v3 : 0.2f * v3; float ex3 = __expf(v3 - mx3); den3 += ex3;
        const float* wr = wh + (size_t)src * 512;
        acc[0] += ex0 * wr[lane];        acc[1] += ex0 * wr[64 + lane];
        acc[2] += ex1 * wr[128 + lane];  acc[3] += ex1 * wr[192 + lane];
        acc[4] += ex2 * wr[256 + lane];  acc[5] += ex2 * wr[320 + lane];
        acc[6] += ex3 * wr[384 + lane];  acc[7] += ex3 * wr[448 + lane];
    }
    den0 += 1e-16f; den1 += 1e-16f; den2 += 1e-16f; den3 += 1e-16f;
    const float o0 = 0.25f * (acc[0] / den0 + acc[2] / den1 + acc[4] / den2 + acc[6] / den3) + bias[lane];
    const float o1 = 0.25f * (acc[1] / den0 + acc[3] / den1 + acc[5] / den2 + acc[7] / den3) + bias[64 + lane];
    outf[(size_t)d * 128 + lane] = fmaxf(o0, 0.f);
    outf[(size_t)d * 128 + 64 + lane] = fmaxf(o1, 0.f);
}

// ---------------- final FC: one wave / node ----------------
__global__ __launch_bounds__(256) void fc_kernel(const float* __restrict__ s,
                                                 const float* __restrict__ fw, const float* __restrict__ fb,
                                                 float* __restrict__ out) {
    const int lane = threadIdx.x & 63;
    const int i = blockIdx.x * 4 + (threadIdx.x >> 6);
    const float v0 = s[(size_t)i * 128 + lane], v1 = s[(size_t)i * 128 + 64 + lane];
    float p[6];
#pragma unroll
    for (int m = 0; m < 6; ++m) p[m] = v0 * fw[m * 128 + lane] + v1 * fw[m * 128 + 64 + lane];
#pragma unroll
    for (int off = 32; off > 0; off >>= 1) {
#pragma unroll
        for (int m = 0; m < 6; ++m) p[m] += __shfl_down(p[m], off);
    }
    if (lane == 0) {
#pragma unroll
        for (int m = 0; m < 6; ++m) out[(size_t)i * 6 + m] = p[m] + fb[m];
    }
}

extern "C" void kernel_launch(void* const* d_in, const int* in_sizes, int n_in,
                              void* d_out, int out_size, void* d_ws, size_t ws_size,
                              hipStream_t stream) {
    const float* x = (const float*)d_in[0];
    const float* wih0 = (const float*)d_in[1];
    const float* whh0 = (const float*)d_in[2];
    const float* bih0 = (const float*)d_in[3];
    const float* bhh0 = (const float*)d_in[4];
    const float* wih1 = (const float*)d_in[5];
    const float* whh1 = (const float*)d_in[6];
    const float* bih1 = (const float*)d_in[7];
    const float* bhh1 = (const float*)d_in[8];
    const float* g1w = (const float*)d_in[9];
    const float* g1as = (const float*)d_in[10];
    const float* g1ad = (const float*)d_in[11];
    const float* g1b = (const float*)d_in[12];
    const float* g2w = (const float*)d_in[13];
    const float* g2as = (const float*)d_in[14];
    const float* g2ad = (const float*)d_in[15];
    const float* g2b = (const float*)d_in[16];
    const float* fcw = (const float*)d_in[17];
    const float* fcb = (const float*)d_in[18];
    const int* eidx = (const int*)d_in[19];
    const int* edge0 = eidx;
    const int* edge1 = eidx + E_EDGES;

    char* ws = (char*)d_ws;
    float* H0 = (float*)ws;                               // 40000*128 f32
    float* H1 = (float*)(ws + 20480000);                  // 40000*128 f32
    float* WH = (float*)(ws + 40960000);                  // 40000*512 f32
    float* AS = (float*)(ws + 122880000);                 // 40000*4 f32
    float* AD = (float*)(ws + 123520000);                 // 40000*4 f32
    short* PK = (short*)(ws + 124160000);                 // 159744 bf16 (packed weights)
    int* OFFS = (int*)(ws + 124765184);                   // 40001 int
    int* CURS = (int*)(ws + 124925248);                   // 40000 int (also cnt)
    int* ESORT = (int*)(ws + 125085248);                  // 680000 int

    hipMemsetAsync(CURS, 0, BN_TOTAL * sizeof(int), stream);
    pack_w<<<624, 256, 0, stream>>>(wih0, whh0, wih1, whh1, PK);
    csr_count<<<(NE + 255) / 256, 256, 0, stream>>>(edge1, CURS);
    csr_scan<<<1, 1024, 0, stream>>>(CURS, OFFS, CURS);
    csr_fill<<<(NE + 255) / 256, 256, 0, stream>>>(edge1, CURS, ESORT);

    gru_mfma<<<GRU_BLOCKS, 512, 0, stream>>>(x, PK, bih0, bhh0, bih1, bhh1, H0);

    dim3 gg(625, 8);
    gat_gemm<<<gg, 256, 0, stream>>>(H0, g1w, WH);
    gat_alpha<<<10000, 256, 0, stream>>>(WH, g1as, g1ad, AS, AD);
    gat_aggregate<<<10000, 256, 0, stream>>>(WH, AS, AD, OFFS, ESORT, edge0, g1b, H1);

    gat_gemm<<<gg, 256, 0, stream>>>(H1, g2w, WH);
    gat_alpha<<<10000, 256, 0, stream>>>(WH, g2as, g2ad, AS, AD);
    gat_aggregate<<<10000, 256, 0, stream>>>(WH, AS, AD, OFFS, ESORT, edge0, g2b, H0);

    fc_kernel<<<10000, 256, 0, stream>>>(H0, fcw, fcb, (float*)d_out);
}

// Round 5
// 1523.495 us; speedup vs baseline: 4.1191x; 1.6873x over previous
//
#include <hip/hip_runtime.h>
#include <math.h>

#define T_STEPS 24
#define F_IN 10
#define HDIM 128
#define E_EDGES 80000
#define B_BATCH 8
#define N_NODES 5000
#define BN_TOTAL 40000
#define BE 640000
#define NE 680000

typedef __attribute__((ext_vector_type(8))) short s16x8;
typedef __attribute__((ext_vector_type(4))) short s16x4;
typedef __attribute__((ext_vector_type(4))) float fx4;
typedef __attribute__((ext_vector_type(2))) float fx2;

__device__ __forceinline__ float sigmoidf_(float v) { return 1.f / (1.f + __expf(-v)); }
__device__ __forceinline__ float tanhf_(float v) { float e = __expf(2.f * v); return 1.f - 2.f / (e + 1.f); }

__device__ __forceinline__ short f2b(float f) {
    unsigned u = __float_as_uint(f);
    unsigned r = (u + 0x7fffu + ((u >> 16) & 1u)) >> 16;
    return (short)r;
}

#define VMW0 asm volatile("s_waitcnt vmcnt(0)" ::: "memory")

// ---------------- pack weights into MFMA A-fragment order (bf16), nf-major ----------------
// shorts: [0,49152) hh0 ; [49152,98304) hh1 ; [98304,147456) ih1 ; [147456,159744) ih0(K pad 10->32)
//         [159744,225280) g1w ; [225280,290816) g2w
// K=128 mats: idx-in-mat = ((nf*4+kf)*64+lane)*8+j -> W[nf*16+(lane&15)][kf*32+(lane>>4)*8+j]
__global__ void pack_w(const float* __restrict__ wih0, const float* __restrict__ whh0,
                       const float* __restrict__ wih1, const float* __restrict__ whh1,
                       const float* __restrict__ g1w, const float* __restrict__ g2w,
                       short* __restrict__ pk) {
    int id = blockIdx.x * 256 + threadIdx.x;
    if (id >= 290816) return;
    if (id < 147456) {
        int mat = id / 49152, r = id % 49152;
        int nf = r / 2048, r2 = r % 2048, kf = r2 / 512, r3 = r2 % 512, lane = r3 / 8, j = r3 % 8;
        int n = nf * 16 + (lane & 15), k = kf * 32 + (lane >> 4) * 8 + j;
        const float* src = (mat == 0) ? whh0 : (mat == 1) ? whh1 : wih1;
        pk[id] = f2b(src[n * 128 + k]);
    } else if (id < 159744) {
        int r = id - 147456;
        int nf = r / 512, r2 = r % 512, lane = r2 / 8, j = r2 % 8;
        int n = nf * 16 + (lane & 15), k = (lane >> 4) * 8 + j;
        pk[id] = (k < F_IN) ? f2b(wih0[n * F_IN + k]) : (short)0;
    } else {
        const float* src = (id < 225280) ? g1w : g2w;
        int r = (id < 225280) ? (id - 159744) : (id - 225280);
        int nf = r / 2048, r2 = r % 2048, kf = r2 / 512, r3 = r2 % 512, lane = r3 / 8, j = r3 % 8;
        int n = nf * 16 + (lane & 15), k = kf * 32 + (lane >> 4) * 8 + j;
        pk[id] = f2b(src[n * 128 + k]);
    }
}

// ---------------- fused 2-layer GRU; 64 seqs/block, weights stationary ----------------
// 8 waves; wave w owns output cols [w*16, w*16+16). hh0/hh1 frags in VGPR; ih0/ih1 LDS-resident.
__global__ __launch_bounds__(512, 2) void gru_mfma(
    const float* __restrict__ x, const short* __restrict__ pk,
    const float* __restrict__ bih0, const float* __restrict__ bhh0,
    const float* __restrict__ bih1, const float* __restrict__ bhh1,
    float* __restrict__ temporal) {
    __shared__ __align__(16) short h1b[64 * 128];     // 16 KB
    __shared__ __align__(16) short h2b[64 * 128];     // 16 KB
    __shared__ __align__(16) short ih1s[49152];       // 96 KB
    __shared__ __align__(16) short ih0s[12288];       // 24 KB
    __shared__ __align__(16) float blds[2][4][128];   // 4 KB
    const int tid = threadIdx.x;
    const int w = tid >> 6, l = tid & 63;
    const int lm = l & 15, lk = l >> 4;
    const int jb = w * 16 + lk * 4;          // this thread's 4 output cols
    const long sb = (long)blockIdx.x * 64;   // 625*64 == 40000 exactly

    // ---- one-time staging: ih1 (96 KB) + ih0 (24 KB) into LDS ----
    {
        const char* src1 = (const char*)(pk + 98304);
#pragma unroll
        for (int r = 0; r < 12; ++r) {
            const int off = (w * 12 + r) * 1024;
            __builtin_amdgcn_global_load_lds(
                (const __attribute__((address_space(1))) unsigned int*)(src1 + off + l * 16),
                (__attribute__((address_space(3))) unsigned int*)((char*)ih1s + off), 16, 0, 0);
        }
        const char* src0 = (const char*)(pk + 147456);
#pragma unroll
        for (int r = 0; r < 3; ++r) {
            const int off = (w * 3 + r) * 1024;
            __builtin_amdgcn_global_load_lds(
                (const __attribute__((address_space(1))) unsigned int*)(src0 + off + l * 16),
                (__attribute__((address_space(3))) unsigned int*)((char*)ih0s + off), 16, 0, 0);
        }
    }
    if (tid < 128) {
        const int j = tid;
        blds[0][0][j] = bih0[j] + bhh0[j];
        blds[0][1][j] = bih0[128 + j] + bhh0[128 + j];
        blds[0][2][j] = bhh0[256 + j];
        blds[0][3][j] = bih0[256 + j];
    } else if (tid < 256) {
        const int j = tid - 128;
        blds[1][0][j] = bih1[j] + bhh1[j];
        blds[1][1][j] = bih1[128 + j] + bhh1[128 + j];
        blds[1][2][j] = bhh1[256 + j];
        blds[1][3][j] = bih1[256 + j];
    }
    for (int i = tid; i < 64 * 128; i += 512) { h1b[i] = 0; h2b[i] = 0; }

    // ---- recurrent weights resident in VGPRs ----
    s16x8 whh0r[3][4], whh1r[3][4];
#pragma unroll
    for (int g = 0; g < 3; ++g)
#pragma unroll
        for (int kf = 0; kf < 4; ++kf) {
            const int idx = ((((g * 8 + w) * 4) + kf) * 64 + l) * 8;
            whh0r[g][kf] = *(const s16x8*)&pk[idx];
            whh1r[g][kf] = *(const s16x8*)&pk[49152 + idx];
        }

    fx4 h1s[4], h2s[4];
#pragma unroll
    for (int mf = 0; mf < 4; ++mf) { h1s[mf] = (fx4)(0.f); h2s[mf] = (fx4)(0.f); }

    VMW0;
    __syncthreads();

    for (int tt = 0; tt < T_STEPS; ++tt) {
        // ---- x fragments ----
        fx2 xa[4][4];
#pragma unroll
        for (int mf = 0; mf < 4; ++mf) {
            xa[mf][0] = (fx2)(0.f); xa[mf][1] = (fx2)(0.f); xa[mf][2] = (fx2)(0.f); xa[mf][3] = (fx2)(0.f);
            const float* xr = x + (sb + mf * 16 + lm) * (T_STEPS * F_IN) + tt * F_IN;
            if (lk == 0) {
                xa[mf][0] = *(const fx2*)(xr);     xa[mf][1] = *(const fx2*)(xr + 2);
                xa[mf][2] = *(const fx2*)(xr + 4); xa[mf][3] = *(const fx2*)(xr + 6);
            } else if (lk == 1) {
                xa[mf][0] = *(const fx2*)(xr + 8);
            }
        }
        fx4 acc[4][4];
#pragma unroll
        for (int p = 0; p < 4; ++p) {
            const fx4 bv = *(const fx4*)&blds[0][p][jb];
#pragma unroll
            for (int mf = 0; mf < 4; ++mf) acc[p][mf] = bv;
        }
        // ===== layer 0: hh0 (B = h1 old), parts r,z,nh =====
#pragma unroll
        for (int kf = 0; kf < 4; ++kf) {
            s16x8 bfr[4];
#pragma unroll
            for (int mf = 0; mf < 4; ++mf) {
                const int m = mf * 16 + lm;
                const int slot = (kf * 4 + lk) ^ (m & 7);
                bfr[mf] = *(const s16x8*)&h1b[m * 128 + slot * 8];
            }
#pragma unroll
            for (int g = 0; g < 3; ++g) {
                const int part = (g == 2) ? 2 : g;
#pragma unroll
                for (int mf = 0; mf < 4; ++mf)
                    acc[part][mf] = __builtin_amdgcn_mfma_f32_16x16x32_bf16(whh0r[g][kf], bfr[mf], acc[part][mf], 0, 0, 0);
            }
        }
        // ---- ih0 (A LDS-resident, B = x frags), parts r,z,ni ----
        s16x8 xfr[4];
#pragma unroll
        for (int mf = 0; mf < 4; ++mf) {
            s16x8 t = { f2b(xa[mf][0].x), f2b(xa[mf][0].y), f2b(xa[mf][1].x), f2b(xa[mf][1].y),
                        f2b(xa[mf][2].x), f2b(xa[mf][2].y), f2b(xa[mf][3].x), f2b(xa[mf][3].y) };
            xfr[mf] = t;
        }
#pragma unroll
        for (int g = 0; g < 3; ++g) {
            const int part = (g == 2) ? 3 : g;
            const s16x8 af = *(const s16x8*)&ih0s[((g * 8 + w) * 64 + l) * 8];
#pragma unroll
            for (int mf = 0; mf < 4; ++mf)
                acc[part][mf] = __builtin_amdgcn_mfma_f32_16x16x32_bf16(af, xfr[mf], acc[part][mf], 0, 0, 0);
        }
        // ---- elementwise layer 0 -> h1 (fp32 state), pack bf16 ----
        s16x4 w1[4];
#pragma unroll
        for (int mf = 0; mf < 4; ++mf) {
#pragma unroll
            for (int rg = 0; rg < 4; ++rg) {
                const float r = sigmoidf_(acc[0][mf][rg]);
                const float z = sigmoidf_(acc[1][mf][rg]);
                const float n = tanhf_(acc[3][mf][rg] + r * acc[2][mf][rg]);
                h1s[mf][rg] = (1.f - z) * n + z * h1s[mf][rg];
            }
            s16x4 p4 = { f2b(h1s[mf][0]), f2b(h1s[mf][1]), f2b(h1s[mf][2]), f2b(h1s[mf][3]) };
            w1[mf] = p4;
        }
        // ===== layer 1: hh1 (B = h2 old), parts r,z,nh =====
#pragma unroll
        for (int p = 0; p < 4; ++p) {
            const fx4 bv = *(const fx4*)&blds[1][p][jb];
#pragma unroll
            for (int mf = 0; mf < 4; ++mf) acc[p][mf] = bv;
        }
#pragma unroll
        for (int kf = 0; kf < 4; ++kf) {
            s16x8 bfr[4];
#pragma unroll
            for (int mf = 0; mf < 4; ++mf) {
                const int m = mf * 16 + lm;
                const int slot = (kf * 4 + lk) ^ (m & 7);
                bfr[mf] = *(const s16x8*)&h2b[m * 128 + slot * 8];
            }
#pragma unroll
            for (int g = 0; g < 3; ++g) {
                const int part = (g == 2) ? 2 : g;
#pragma unroll
                for (int mf = 0; mf < 4; ++mf)
                    acc[part][mf] = __builtin_amdgcn_mfma_f32_16x16x32_bf16(whh1r[g][kf], bfr[mf], acc[part][mf], 0, 0, 0);
            }
        }
        __syncthreads();   // all reads of h1b(old)/h2b(old) complete
#pragma unroll
        for (int mf = 0; mf < 4; ++mf) {
            const int m = mf * 16 + lm;
            const int slot = (jb >> 3) ^ (m & 7);
            *(s16x4*)&h1b[m * 128 + slot * 8 + (jb & 7)] = w1[mf];
        }
        __syncthreads();   // h1 new visible
        // ===== layer 1: ih1 (A LDS-resident, B = h1 new), parts r,z,ni =====
#pragma unroll
        for (int kf = 0; kf < 4; ++kf) {
            s16x8 bfr[4];
#pragma unroll
            for (int mf = 0; mf < 4; ++mf) {
                const int m = mf * 16 + lm;
                const int slot = (kf * 4 + lk) ^ (m & 7);
                bfr[mf] = *(const s16x8*)&h1b[m * 128 + slot * 8];
            }
#pragma unroll
            for (int g = 0; g < 3; ++g) {
                const int part = (g == 2) ? 3 : g;
                const s16x8 af = *(const s16x8*)&ih1s[((((g * 8 + w) * 4) + kf) * 64 + l) * 8];
#pragma unroll
                for (int mf = 0; mf < 4; ++mf)
                    acc[part][mf] = __builtin_amdgcn_mfma_f32_16x16x32_bf16(af, bfr[mf], acc[part][mf], 0, 0, 0);
            }
        }
        // ---- elementwise layer 1 -> h2, publish ----
#pragma unroll
        for (int mf = 0; mf < 4; ++mf) {
#pragma unroll
            for (int rg = 0; rg < 4; ++rg) {
                const float r = sigmoidf_(acc[0][mf][rg]);
                const float z = sigmoidf_(acc[1][mf][rg]);
                const float n = tanhf_(acc[3][mf][rg] + r * acc[2][mf][rg]);
                h2s[mf][rg] = (1.f - z) * n + z * h2s[mf][rg];
            }
            const int m = mf * 16 + lm;
            const int slot = (jb >> 3) ^ (m & 7);
            s16x4 p4 = { f2b(h2s[mf][0]), f2b(h2s[mf][1]), f2b(h2s[mf][2]), f2b(h2s[mf][3]) };
            *(s16x4*)&h2b[m * 128 + slot * 8 + (jb & 7)] = p4;
        }
        __syncthreads();   // h2 new visible for next step
    }
#pragma unroll
    for (int mf = 0; mf < 4; ++mf) {
        const long m = sb + mf * 16 + lm;
        *(fx4*)&temporal[m * 128 + jb] = h2s[mf];
    }
}

// ---------------- CSR build ----------------
__global__ void csr_count(const int* __restrict__ edge1, int* __restrict__ cnt) {
    int e = blockIdx.x * 256 + threadIdx.x;
    if (e >= NE) return;
    int d;
    if (e < BE) { int b = e / E_EDGES; d = edge1[e - b * E_EDGES] + b * N_NODES; }
    else d = e - BE;
    atomicAdd(&cnt[d], 1);
}

__global__ void csr_scan(const int* cnt, int* offs, int* curs) {
    __shared__ int part[1024];
    const int t = threadIdx.x;
    const int base = t * 40;
    int end = base + 40; if (end > BN_TOTAL) end = BN_TOTAL;
    int s = 0;
    for (int i = base; i < end; ++i) s += cnt[i];
    part[t] = s;
    __syncthreads();
    for (int off = 1; off < 1024; off <<= 1) {
        int v = (t >= off) ? part[t - off] : 0;
        __syncthreads();
        part[t] += v;
        __syncthreads();
    }
    int run = part[t] - s;
    for (int i = base; i < end; ++i) {
        int c = cnt[i];
        offs[i] = run; curs[i] = run; run += c;
    }
    if (t == 1023) offs[BN_TOTAL] = NE;
}

__global__ void csr_fill(const int* __restrict__ edge1, int* __restrict__ curs, int* __restrict__ esort) {
    int e = blockIdx.x * 256 + threadIdx.x;
    if (e >= NE) return;
    int d;
    if (e < BE) { int b = e / E_EDGES; d = edge1[e - b * E_EDGES] + b * N_NODES; }
    else d = e - BE;
    int pos = atomicAdd(&curs[d], 1);
    esort[pos] = e;
}

// ---------------- GAT: wh = feat @ W.T via MFMA (128x128 tile), fp32 out ----------------
__global__ __launch_bounds__(256, 2) void gat_gemm(const float* __restrict__ feat,
                                                   const short* __restrict__ pkg,
                                                   float* __restrict__ wh) {
    __shared__ __align__(16) short fb[128 * 128];   // 32 KB bf16, XOR-swizzled
    const int tid = threadIdx.x;
    const int w = tid >> 6, l = tid & 63;
    const int lm = l & 15, lk = l >> 4;
    const int i0 = blockIdx.x * 128;
    const int j0 = blockIdx.y * 128;
    // stage feat tile (rows >= 40000 -> zeros)
#pragma unroll
    for (int it = 0; it < 16; ++it) {
        const int idx = it * 256 + tid;        // 4096 fx4
        const int r = idx >> 5, kq = idx & 31; // k = kq*4
        fx4 v = (fx4)(0.f);
        const int row = i0 + r;
        if (row < BN_TOTAL) v = *(const fx4*)&feat[(size_t)row * 128 + kq * 4];
        const int slot = (kq >> 1) ^ (r & 7);
        s16x4 pv = { f2b(v.x), f2b(v.y), f2b(v.z), f2b(v.w) };
        *(s16x4*)&fb[r * 128 + slot * 8 + (kq & 1) * 4] = pv;
    }
    __syncthreads();
    fx4 acc[2][8];
#pragma unroll
    for (int jf = 0; jf < 2; ++jf)
#pragma unroll
        for (int mf = 0; mf < 8; ++mf) acc[jf][mf] = (fx4)(0.f);
#pragma unroll
    for (int kf = 0; kf < 4; ++kf) {
        s16x8 bfr[8];
#pragma unroll
        for (int mf = 0; mf < 8; ++mf) {
            const int m = mf * 16 + lm;
            const int slot = (kf * 4 + lk) ^ (m & 7);
            bfr[mf] = *(const s16x8*)&fb[m * 128 + slot * 8];
        }
#pragma unroll
        for (int jf = 0; jf < 2; ++jf) {
            const int nf = (j0 >> 4) + w * 2 + jf;
            const s16x8 af = *(const s16x8*)&pkg[((nf * 4 + kf) * 64 + l) * 8];
#pragma unroll
            for (int mf = 0; mf < 8; ++mf)
                acc[jf][mf] = __builtin_amdgcn_mfma_f32_16x16x32_bf16(af, bfr[mf], acc[jf][mf], 0, 0, 0);
        }
    }
#pragma unroll
    for (int jf = 0; jf < 2; ++jf) {
        const int nb = j0 + w * 32 + jf * 16 + lk * 4;
#pragma unroll
        for (int mf = 0; mf < 8; ++mf) {
            const int m = i0 + mf * 16 + lm;
            if (m < BN_TOTAL) *(fx4*)&wh[(size_t)m * 512 + nb] = acc[jf][mf];
        }
    }
}

// ---------------- per-node alpha_src / alpha_dst ----------------
__global__ __launch_bounds__(256) void gat_alpha(const float* __restrict__ wh,
                                                 const float* __restrict__ asrc, const float* __restrict__ adst,
                                                 float* __restrict__ AS, float* __restrict__ AD) {
    const int lane = threadIdx.x & 63;
    const int node = blockIdx.x * 4 + (threadIdx.x >> 6);
    const float* r = wh + (size_t)node * 512;
    float ps[4], pd[4];
#pragma unroll
    for (int hd = 0; hd < 4; ++hd) {
        float w0 = r[hd * 128 + lane], w1 = r[hd * 128 + 64 + lane];
        ps[hd] = w0 * asrc[hd * 128 + lane] + w1 * asrc[hd * 128 + 64 + lane];
        pd[hd] = w0 * adst[hd * 128 + lane] + w1 * adst[hd * 128 + 64 + lane];
    }
#pragma unroll
    for (int off = 32; off > 0; off >>= 1) {
#pragma unroll
        for (int hd = 0; hd < 4; ++hd) {
            ps[hd] += __shfl_down(ps[hd], off);
            pd[hd] += __shfl_down(pd[hd], off);
        }
    }
    if (lane == 0) {
#pragma unroll
        for (int hd = 0; hd < 4; ++hd) { AS[node * 4 + hd] = ps[hd]; AD[node * 4 + hd] = pd[hd]; }
    }
}

__device__ __forceinline__ int decode_src(int eid, const int* __restrict__ edge0) {
    if (eid < BE) { int b = eid / E_EDGES; return edge0[eid - b * E_EDGES] + b * N_NODES; }
    return eid - BE;
}

// ---------------- per-node softmax attention + aggregate (one wave / node) ----------------
// batch<->XCD affinity: d = (bid&7)*5000 + (bid>>3)*4 + wid  (bid%8 ~ XCD id)
__global__ __launch_bounds__(256) void gat_aggregate(const float* __restrict__ wh,
                                                     const float* __restrict__ AS, const float* __restrict__ AD,
                                                     const int* __restrict__ offs, const int* __restrict__ esort,
                                                     const int* __restrict__ edge0, const float* __restrict__ bias,
                                                     float* __restrict__ outf) {
    const int lane = threadIdx.x & 63;
    const int bid = blockIdx.x;
    const int d = (bid & 7) * N_NODES + (bid >> 3) * 4 + (threadIdx.x >> 6);
    const int e0 = offs[d], e1 = offs[d + 1];
    const float ad0 = AD[d * 4 + 0], ad1 = AD[d * 4 + 1], ad2 = AD[d * 4 + 2], ad3 = AD[d * 4 + 3];
    float mx0 = -1e30f, mx1 = -1e30f, mx2 = -1e30f, mx3 = -1e30f;
    for (int e = e0; e < e1; ++e) {
        const int src = decode_src(esort[e], edge0);
        float v0 = AS[src * 4 + 0] + ad0; v0 = v0 > 0.f ? v0 : 0.2f * v0; mx0 = fmaxf(mx0, v0);
        float v1 = AS[src * 4 + 1] + ad1; v1 = v1 > 0.f ? v1 : 0.2f * v1; mx1 = fmaxf(mx1, v1);
        float v2 = AS[src * 4 + 2] + ad2; v2 = v2 > 0.f ? v2 : 0.2f * v2; mx2 = fmaxf(mx2, v2);
        float v3 = AS[src * 4 + 3] + ad3; v3 = v3 > 0.f ? v3 : 0.2f * v3; mx3 = fmaxf(mx3, v3);
    }
    float den0 = 0.f, den1 = 0.f, den2 = 0.f, den3 = 0.f;
    float acc[8] = {0.f, 0.f, 0.f, 0.f, 0.f, 0.f, 0.f, 0.f};
    for (int e = e0; e < e1; ++e) {
        const int src = decode_src(esort[e], edge0);
        float v0 = AS[src * 4 + 0] + ad0; v0 = v0 > 0.f ? v0 : 0.2f * v0; float ex0 = __expf(v0 - mx0); den0 += ex0;
        float v1 = AS[src * 4 + 1] + ad1; v1 = v1 > 0.f ? v1 : 0.2f * v1; float ex1 = __expf(v1 - mx1); den1 += ex1;
        float v2 = AS[src * 4 + 2] + ad2; v2 = v2 > 0.f ? v2 : 0.2f * v2; float ex2 = __expf(v2 - mx2); den2 += ex2;
        float v3 = AS[src * 4 + 3] + ad3; v3 = v3 > 0.f ? v3 : 0.2f * v3; float ex3 = __expf(v3 - mx3); den3 += ex3;
        const float* wr = wh + (size_t)src * 512;
        acc[0] += ex0 * wr[lane];        acc[1] += ex0 * wr[64 + lane];
        acc[2] += ex1 * wr[128 + lane];  acc[3] += ex1 * wr[192 + lane];
        acc[4] += ex2 * wr[256 + lane];  acc[5] += ex2 * wr[320 + lane];
        acc[6] += ex3 * wr[384 + lane];  acc[7] += ex3 * wr[448 + lane];
    }
    den0 += 1e-16f; den1 += 1e-16f; den2 += 1e-16f; den3 += 1e-16f;
    const float o0 = 0.25f * (acc[0] / den0 + acc[2] / den1 + acc[4] / den2 + acc[6] / den3) + bias[lane];
    const float o1 = 0.25f * (acc[1] / den0 + acc[3] / den1 + acc[5] / den2 + acc[7] / den3) + bias[64 + lane];
    outf[(size_t)d * 128 + lane] = fmaxf(o0, 0.f);
    outf[(size_t)d * 128 + 64 + lane] = fmaxf(o1, 0.f);
}

// ---------------- final FC: one wave / node ----------------
__global__ __launch_bounds__(256) void fc_kernel(const float* __restrict__ s,
                                                 const float* __restrict__ fw, const float* __restrict__ fb,
                                                 float* __restrict__ out) {
    const int lane = threadIdx.x & 63;
    const int i = blockIdx.x * 4 + (threadIdx.x >> 6);
    const float v0 = s[(size_t)i * 128 + lane], v1 = s[(size_t)i * 128 + 64 + lane];
    float p[6];
#pragma unroll
    for (int m = 0; m < 6; ++m) p[m] = v0 * fw[m * 128 + lane] + v1 * fw[m * 128 + 64 + lane];
#pragma unroll
    for (int off = 32; off > 0; off >>= 1) {
#pragma unroll
        for (int m = 0; m < 6; ++m) p[m] += __shfl_down(p[m], off);
    }
    if (lane == 0) {
#pragma unroll
        for (int m = 0; m < 6; ++m) out[(size_t)i * 6 + m] = p[m] + fb[m];
    }
}

extern "C" void kernel_launch(void* const* d_in, const int* in_sizes, int n_in,
                              void* d_out, int out_size, void* d_ws, size_t ws_size,
                              hipStream_t stream) {
    const float* x = (const float*)d_in[0];
    const float* wih0 = (const float*)d_in[1];
    const float* whh0 = (const float*)d_in[2];
    const float* bih0 = (const float*)d_in[3];
    const float* bhh0 = (const float*)d_in[4];
    const float* wih1 = (const float*)d_in[5];
    const float* whh1 = (const float*)d_in[6];
    const float* bih1 = (const float*)d_in[7];
    const float* bhh1 = (const float*)d_in[8];
    const float* g1w = (const float*)d_in[9];
    const float* g1as = (const float*)d_in[10];
    const float* g1ad = (const float*)d_in[11];
    const float* g1b = (const float*)d_in[12];
    const float* g2w = (const float*)d_in[13];
    const float* g2as = (const float*)d_in[14];
    const float* g2ad = (const float*)d_in[15];
    const float* g2b = (const float*)d_in[16];
    const float* fcw = (const float*)d_in[17];
    const float* fcb = (const float*)d_in[18];
    const int* eidx = (const int*)d_in[19];
    const int* edge0 = eidx;
    const int* edge1 = eidx + E_EDGES;

    char* ws = (char*)d_ws;
    float* H0 = (float*)ws;                               // 40000*128 f32
    float* H1 = (float*)(ws + 20480000);                  // 40000*128 f32
    float* WH = (float*)(ws + 40960000);                  // 40000*512 f32
    float* AS = (float*)(ws + 122880000);                 // 40000*4 f32
    float* AD = (float*)(ws + 123520000);                 // 40000*4 f32
    short* PK = (short*)(ws + 124160000);                 // 290816 bf16 packed weights
    int* OFFS = (int*)(ws + 124765184);                   // 40001 int
    int* CURS = (int*)(ws + 124925248);                   // 40000 int (also cnt)
    int* ESORT = (int*)(ws + 125085248);                  // 680000 int

    hipMemsetAsync(CURS, 0, BN_TOTAL * sizeof(int), stream);
    pack_w<<<1136, 256, 0, stream>>>(wih0, whh0, wih1, whh1, g1w, g2w, PK);
    csr_count<<<(NE + 255) / 256, 256, 0, stream>>>(edge1, CURS);
    csr_scan<<<1, 1024, 0, stream>>>(CURS, OFFS, CURS);
    csr_fill<<<(NE + 255) / 256, 256, 0, stream>>>(edge1, CURS, ESORT);

    gru_mfma<<<625, 512, 0, stream>>>(x, PK, bih0, bhh0, bih1, bhh1, H0);

    dim3 gg(313, 4);
    gat_gemm<<<gg, 256, 0, stream>>>(H0, PK + 159744, WH);
    gat_alpha<<<10000, 256, 0, stream>>>(WH, g1as, g1ad, AS, AD);
    gat_aggregate<<<10000, 256, 0, stream>>>(WH, AS, AD, OFFS, ESORT, edge0, g1b, H1);

    gat_gemm<<<gg, 256, 0, stream>>>(H1, PK + 225280, WH);
    gat_alpha<<<10000, 256, 0, stream>>>(WH, g2as, g2ad, AS, AD);
    gat_aggregate<<<10000, 256, 0, stream>>>(WH, AS, AD, OFFS, ESORT, edge0, g2b, H0);

    fc_kernel<<<10000, 256, 0, stream>>>(H0, fcw, fcb, (float*)d_out);
}

// Round 7
// 1348.506 us; speedup vs baseline: 4.6536x; 1.1298x over previous
//
#include <hip/hip_runtime.h>
#include <math.h>

#define T_STEPS 24
#define F_IN 10
#define HDIM 128
#define E_EDGES 80000
#define B_BATCH 8
#define N_NODES 5000
#define BN_TOTAL 40000
#define BE 640000
#define NE 680000

typedef __attribute__((ext_vector_type(8))) short s16x8;
typedef __attribute__((ext_vector_type(4))) short s16x4;
typedef __attribute__((ext_vector_type(4))) float fx4;
typedef __attribute__((ext_vector_type(2))) float fx2;

__device__ __forceinline__ float sigmoidf_(float v) { return 1.f / (1.f + __expf(-v)); }
__device__ __forceinline__ float tanhf_(float v) { float e = __expf(2.f * v); return 1.f - 2.f / (e + 1.f); }

__device__ __forceinline__ short f2b(float f) {
    unsigned u = __float_as_uint(f);
    unsigned r = (u + 0x7fffu + ((u >> 16) & 1u)) >> 16;
    return (short)r;
}

#define VMW0 asm volatile("s_waitcnt vmcnt(0)" ::: "memory")

// ---------------- pack weights into MFMA A-fragment order (bf16), nf-major ----------------
// shorts: [0,49152) hh0 ; [49152,98304) hh1 ; [98304,147456) ih1 ; [147456,159744) ih0(K pad 10->32)
//         [159744,225280) g1w ; [225280,290816) g2w
// K=128 mats: idx-in-mat = ((nf*4+kf)*64+lane)*8+j -> W[nf*16+(lane&15)][kf*32+(lane>>4)*8+j]
__global__ void pack_w(const float* __restrict__ wih0, const float* __restrict__ whh0,
                       const float* __restrict__ wih1, const float* __restrict__ whh1,
                       const float* __restrict__ g1w, const float* __restrict__ g2w,
                       short* __restrict__ pk) {
    int id = blockIdx.x * 256 + threadIdx.x;
    if (id >= 290816) return;
    if (id < 147456) {
        int mat = id / 49152, r = id % 49152;
        int nf = r / 2048, r2 = r % 2048, kf = r2 / 512, r3 = r2 % 512, lane = r3 / 8, j = r3 % 8;
        int n = nf * 16 + (lane & 15), k = kf * 32 + (lane >> 4) * 8 + j;
        const float* src = (mat == 0) ? whh0 : (mat == 1) ? whh1 : wih1;
        pk[id] = f2b(src[n * 128 + k]);
    } else if (id < 159744) {
        int r = id - 147456;
        int nf = r / 512, r2 = r % 512, lane = r2 / 8, j = r2 % 8;
        int n = nf * 16 + (lane & 15), k = (lane >> 4) * 8 + j;
        pk[id] = (k < F_IN) ? f2b(wih0[n * F_IN + k]) : (short)0;
    } else {
        const float* src = (id < 225280) ? g1w : g2w;
        int r = (id < 225280) ? (id - 159744) : (id - 225280);
        int nf = r / 2048, r2 = r % 2048, kf = r2 / 512, r3 = r2 % 512, lane = r3 / 8, j = r3 % 8;
        int n = nf * 16 + (lane & 15), k = kf * 32 + (lane >> 4) * 8 + j;
        pk[id] = f2b(src[n * 128 + k]);
    }
}

// ---------------- fused 2-layer GRU; 64 seqs/block, weights stationary ----------------
// 8 waves; wave w owns output cols [w*16, w*16+16). hh0/hh1 frags in VGPR; ih0/ih1 LDS-resident.
// launch_bounds(512,1): VGPR cap 256 (block still schedulable: 8 waves / 4 SIMDs = 2 waves/SIMD).
__global__ __launch_bounds__(512, 1) void gru_mfma(
    const float* __restrict__ x, const short* __restrict__ pk,
    const float* __restrict__ bih0, const float* __restrict__ bhh0,
    const float* __restrict__ bih1, const float* __restrict__ bhh1,
    float* __restrict__ temporal) {
    __shared__ __align__(16) short h1b[64 * 128];     // 16 KB
    __shared__ __align__(16) short h2b[64 * 128];     // 16 KB
    __shared__ __align__(16) short ih1s[49152];       // 96 KB
    __shared__ __align__(16) short ih0s[12288];       // 24 KB
    __shared__ __align__(16) float blds[2][4][128];   // 4 KB
    const int tid = threadIdx.x;
    const int w = tid >> 6, l = tid & 63;
    const int lm = l & 15, lk = l >> 4;
    const int jb = w * 16 + lk * 4;          // this thread's 4 output cols
    const long sb = (long)blockIdx.x * 64;   // 625*64 == 40000 exactly

    // ---- one-time staging: ih1 (96 KB) + ih0 (24 KB) into LDS ----
    {
        const char* src1 = (const char*)(pk + 98304);
#pragma unroll
        for (int r = 0; r < 12; ++r) {
            const int off = (w * 12 + r) * 1024;
            __builtin_amdgcn_global_load_lds(
                (const __attribute__((address_space(1))) unsigned int*)(src1 + off + l * 16),
                (__attribute__((address_space(3))) unsigned int*)((char*)ih1s + off), 16, 0, 0);
        }
        const char* src0 = (const char*)(pk + 147456);
#pragma unroll
        for (int r = 0; r < 3; ++r) {
            const int off = (w * 3 + r) * 1024;
            __builtin_amdgcn_global_load_lds(
                (const __attribute__((address_space(1))) unsigned int*)(src0 + off + l * 16),
                (__attribute__((address_space(3))) unsigned int*)((char*)ih0s + off), 16, 0, 0);
        }
    }
    if (tid < 128) {
        const int j = tid;
        blds[0][0][j] = bih0[j] + bhh0[j];
        blds[0][1][j] = bih0[128 + j] + bhh0[128 + j];
        blds[0][2][j] = bhh0[256 + j];
        blds[0][3][j] = bih0[256 + j];
    } else if (tid < 256) {
        const int j = tid - 128;
        blds[1][0][j] = bih1[j] + bhh1[j];
        blds[1][1][j] = bih1[128 + j] + bhh1[128 + j];
        blds[1][2][j] = bhh1[256 + j];
        blds[1][3][j] = bih1[256 + j];
    }
    for (int i = tid; i < 64 * 128; i += 512) { h1b[i] = 0; h2b[i] = 0; }

    // ---- recurrent weights resident in VGPRs ----
    s16x8 whh0r[3][4], whh1r[3][4];
#pragma unroll
    for (int g = 0; g < 3; ++g)
#pragma unroll
        for (int kf = 0; kf < 4; ++kf) {
            const int idx = ((((g * 8 + w) * 4) + kf) * 64 + l) * 8;
            whh0r[g][kf] = *(const s16x8*)&pk[idx];
            whh1r[g][kf] = *(const s16x8*)&pk[49152 + idx];
        }

    fx4 h1s[4], h2s[4];
#pragma unroll
    for (int mf = 0; mf < 4; ++mf) { h1s[mf] = (fx4)(0.f); h2s[mf] = (fx4)(0.f); }

    VMW0;
    __syncthreads();

    for (int tt = 0; tt < T_STEPS; ++tt) {
        // ---- x loads (issued early, consumed after hh0) ----
        fx2 xa[4][4];
#pragma unroll
        for (int mf = 0; mf < 4; ++mf) {
            xa[mf][0] = (fx2)(0.f); xa[mf][1] = (fx2)(0.f); xa[mf][2] = (fx2)(0.f); xa[mf][3] = (fx2)(0.f);
            const float* xr = x + (sb + mf * 16 + lm) * (T_STEPS * F_IN) + tt * F_IN;
            if (lk == 0) {
                xa[mf][0] = *(const fx2*)(xr);     xa[mf][1] = *(const fx2*)(xr + 2);
                xa[mf][2] = *(const fx2*)(xr + 4); xa[mf][3] = *(const fx2*)(xr + 6);
            } else if (lk == 1) {
                xa[mf][0] = *(const fx2*)(xr + 8);
            }
        }
        fx4 acc[4][4];
#pragma unroll
        for (int p = 0; p < 4; ++p) {
            const fx4 bv = *(const fx4*)&blds[0][p][jb];
#pragma unroll
            for (int mf = 0; mf < 4; ++mf) acc[p][mf] = bv;
        }
        // ===== layer 0: hh0 (B = h1 old), parts r,z,nh =====
#pragma unroll
        for (int kf = 0; kf < 4; ++kf) {
            s16x8 bfr[4];
#pragma unroll
            for (int mf = 0; mf < 4; ++mf) {
                const int m = mf * 16 + lm;
                const int slot = (kf * 4 + lk) ^ (m & 7);
                bfr[mf] = *(const s16x8*)&h1b[m * 128 + slot * 8];
            }
#pragma unroll
            for (int g = 0; g < 3; ++g) {
                const int part = (g == 2) ? 2 : g;
#pragma unroll
                for (int mf = 0; mf < 4; ++mf)
                    acc[part][mf] = __builtin_amdgcn_mfma_f32_16x16x32_bf16(whh0r[g][kf], bfr[mf], acc[part][mf], 0, 0, 0);
            }
        }
        // ---- ih0 (A LDS-resident, B = x frags), parts r,z,ni ----
        s16x8 xfr[4];
#pragma unroll
        for (int mf = 0; mf < 4; ++mf) {
            s16x8 t = { f2b(xa[mf][0].x), f2b(xa[mf][0].y), f2b(xa[mf][1].x), f2b(xa[mf][1].y),
                        f2b(xa[mf][2].x), f2b(xa[mf][2].y), f2b(xa[mf][3].x), f2b(xa[mf][3].y) };
            xfr[mf] = t;
        }
#pragma unroll
        for (int g = 0; g < 3; ++g) {
            const int part = (g == 2) ? 3 : g;
            const s16x8 af = *(const s16x8*)&ih0s[((g * 8 + w) * 64 + l) * 8];
#pragma unroll
            for (int mf = 0; mf < 4; ++mf)
                acc[part][mf] = __builtin_amdgcn_mfma_f32_16x16x32_bf16(af, xfr[mf], acc[part][mf], 0, 0, 0);
        }
        // ---- elementwise layer 0 -> h1 (fp32 state), pack bf16 ----
        s16x4 w1[4];
#pragma unroll
        for (int mf = 0; mf < 4; ++mf) {
#pragma unroll
            for (int rg = 0; rg < 4; ++rg) {
                const float r = sigmoidf_(acc[0][mf][rg]);
                const float z = sigmoidf_(acc[1][mf][rg]);
                const float n = tanhf_(acc[3][mf][rg] + r * acc[2][mf][rg]);
                h1s[mf][rg] = (1.f - z) * n + z * h1s[mf][rg];
            }
            s16x4 p4 = { f2b(h1s[mf][0]), f2b(h1s[mf][1]), f2b(h1s[mf][2]), f2b(h1s[mf][3]) };
            w1[mf] = p4;
        }
        // ===== layer 1: hh1 (B = h2 old), parts r,z,nh =====
#pragma unroll
        for (int p = 0; p < 4; ++p) {
            const fx4 bv = *(const fx4*)&blds[1][p][jb];
#pragma unroll
            for (int mf = 0; mf < 4; ++mf) acc[p][mf] = bv;
        }
#pragma unroll
        for (int kf = 0; kf < 4; ++kf) {
            s16x8 bfr[4];
#pragma unroll
            for (int mf = 0; mf < 4; ++mf) {
                const int m = mf * 16 + lm;
                const int slot = (kf * 4 + lk) ^ (m & 7);
                bfr[mf] = *(const s16x8*)&h2b[m * 128 + slot * 8];
            }
#pragma unroll
            for (int g = 0; g < 3; ++g) {
                const int part = (g == 2) ? 2 : g;
#pragma unroll
                for (int mf = 0; mf < 4; ++mf)
                    acc[part][mf] = __builtin_amdgcn_mfma_f32_16x16x32_bf16(whh1r[g][kf], bfr[mf], acc[part][mf], 0, 0, 0);
            }
        }
        __syncthreads();   // all reads of h1b(old)/h2b(old) complete
#pragma unroll
        for (int mf = 0; mf < 4; ++mf) {
            const int m = mf * 16 + lm;
            const int slot = (jb >> 3) ^ (m & 7);
            *(s16x4*)&h1b[m * 128 + slot * 8 + (jb & 7)] = w1[mf];
        }
        __syncthreads();   // h1 new visible
        // ===== layer 1: ih1 (A LDS-resident, B = h1 new), parts r,z,ni =====
#pragma unroll
        for (int kf = 0; kf < 4; ++kf) {
            s16x8 bfr[4];
#pragma unroll
            for (int mf = 0; mf < 4; ++mf) {
                const int m = mf * 16 + lm;
                const int slot = (kf * 4 + lk) ^ (m & 7);
                bfr[mf] = *(const s16x8*)&h1b[m * 128 + slot * 8];
            }
#pragma unroll
            for (int g = 0; g < 3; ++g) {
                const int part = (g == 2) ? 3 : g;
                const s16x8 af = *(const s16x8*)&ih1s[((((g * 8 + w) * 4) + kf) * 64 + l) * 8];
#pragma unroll
                for (int mf = 0; mf < 4; ++mf)
                    acc[part][mf] = __builtin_amdgcn_mfma_f32_16x16x32_bf16(af, bfr[mf], acc[part][mf], 0, 0, 0);
            }
        }
        // ---- elementwise layer 1 -> h2, publish ----
#pragma unroll
        for (int mf = 0; mf < 4; ++mf) {
#pragma unroll
            for (int rg = 0; rg < 4; ++rg) {
                const float r = sigmoidf_(acc[0][mf][rg]);
                const float z = sigmoidf_(acc[1][mf][rg]);
                const float n = tanhf_(acc[3][mf][rg] + r * acc[2][mf][rg]);
                h2s[mf][rg] = (1.f - z) * n + z * h2s[mf][rg];
            }
            const int m = mf * 16 + lm;
            const int slot = (jb >> 3) ^ (m & 7);
            s16x4 p4 = { f2b(h2s[mf][0]), f2b(h2s[mf][1]), f2b(h2s[mf][2]), f2b(h2s[mf][3]) };
            *(s16x4*)&h2b[m * 128 + slot * 8 + (jb & 7)] = p4;
        }
        __syncthreads();   // h2 new visible for next step
    }
#pragma unroll
    for (int mf = 0; mf < 4; ++mf) {
        const long m = sb + mf * 16 + lm;
        *(fx4*)&temporal[m * 128 + jb] = h2s[mf];
    }
}

// ---------------- CSR build ----------------
__global__ void csr_count(const int* __restrict__ edge1, int* __restrict__ cnt) {
    int e = blockIdx.x * 256 + threadIdx.x;
    if (e >= NE) return;
    int d;
    if (e < BE) { int b = e / E_EDGES; d = edge1[e - b * E_EDGES] + b * N_NODES; }
    else d = e - BE;
    atomicAdd(&cnt[d], 1);
}

__global__ void csr_scan(const int* cnt, int* offs, int* curs) {
    __shared__ int part[1024];
    const int t = threadIdx.x;
    const int base = t * 40;
    int end = base + 40; if (end > BN_TOTAL) end = BN_TOTAL;
    int s = 0;
    for (int i = base; i < end; ++i) s += cnt[i];
    part[t] = s;
    __syncthreads();
    for (int off = 1; off < 1024; off <<= 1) {
        int v = (t >= off) ? part[t - off] : 0;
        __syncthreads();
        part[t] += v;
        __syncthreads();
    }
    int run = part[t] - s;
    for (int i = base; i < end; ++i) {
        int c = cnt[i];
        offs[i] = run; curs[i] = run; run += c;
    }
    if (t == 1023) offs[BN_TOTAL] = NE;
}

__global__ void csr_fill(const int* __restrict__ edge1, int* __restrict__ curs, int* __restrict__ esort) {
    int e = blockIdx.x * 256 + threadIdx.x;
    if (e >= NE) return;
    int d;
    if (e < BE) { int b = e / E_EDGES; d = edge1[e - b * E_EDGES] + b * N_NODES; }
    else d = e - BE;
    int pos = atomicAdd(&curs[d], 1);
    esort[pos] = e;
}

// ---------------- GAT: wh = feat @ W.T via MFMA (128x128 tile), fp32 out ----------------
__global__ __launch_bounds__(256, 2) void gat_gemm(const float* __restrict__ feat,
                                                   const short* __restrict__ pkg,
                                                   float* __restrict__ wh) {
    __shared__ __align__(16) short fb[128 * 128];   // 32 KB bf16, XOR-swizzled
    const int tid = threadIdx.x;
    const int w = tid >> 6, l = tid & 63;
    const int lm = l & 15, lk = l >> 4;
    const int i0 = blockIdx.x * 128;
    const int j0 = blockIdx.y * 128;
#pragma unroll
    for (int it = 0; it < 16; ++it) {
        const int idx = it * 256 + tid;        // 4096 fx4
        const int r = idx >> 5, kq = idx & 31; // k = kq*4
        fx4 v = (fx4)(0.f);
        const int row = i0 + r;
        if (row < BN_TOTAL) v = *(const fx4*)&feat[(size_t)row * 128 + kq * 4];
        const int slot = (kq >> 1) ^ (r & 7);
        s16x4 pv = { f2b(v.x), f2b(v.y), f2b(v.z), f2b(v.w) };
        *(s16x4*)&fb[r * 128 + slot * 8 + (kq & 1) * 4] = pv;
    }
    __syncthreads();
    fx4 acc[2][8];
#pragma unroll
    for (int jf = 0; jf < 2; ++jf)
#pragma unroll
        for (int mf = 0; mf < 8; ++mf) acc[jf][mf] = (fx4)(0.f);
#pragma unroll
    for (int kf = 0; kf < 4; ++kf) {
        s16x8 bfr[8];
#pragma unroll
        for (int mf = 0; mf < 8; ++mf) {
            const int m = mf * 16 + lm;
            const int slot = (kf * 4 + lk) ^ (m & 7);
            bfr[mf] = *(const s16x8*)&fb[m * 128 + slot * 8];
        }
#pragma unroll
        for (int jf = 0; jf < 2; ++jf) {
            const int nf = (j0 >> 4) + w * 2 + jf;
            const s16x8 af = *(const s16x8*)&pkg[((nf * 4 + kf) * 64 + l) * 8];
#pragma unroll
            for (int mf = 0; mf < 8; ++mf)
                acc[jf][mf] = __builtin_amdgcn_mfma_f32_16x16x32_bf16(af, bfr[mf], acc[jf][mf], 0, 0, 0);
        }
    }
#pragma unroll
    for (int jf = 0; jf < 2; ++jf) {
        const int nb = j0 + w * 32 + jf * 16 + lk * 4;
#pragma unroll
        for (int mf = 0; mf < 8; ++mf) {
            const int m = i0 + mf * 16 + lm;
            if (m < BN_TOTAL) *(fx4*)&wh[(size_t)m * 512 + nb] = acc[jf][mf];
        }
    }
}

// ---------------- per-node alpha_src / alpha_dst ----------------
__global__ __launch_bounds__(256) void gat_alpha(const float* __restrict__ wh,
                                                 const float* __restrict__ asrc, const float* __restrict__ adst,
                                                 float* __restrict__ AS, float* __restrict__ AD) {
    const int lane = threadIdx.x & 63;
    const int node = blockIdx.x * 4 + (threadIdx.x >> 6);
    const float* r = wh + (size_t)node * 512;
    float ps[4], pd[4];
#pragma unroll
    for (int hd = 0; hd < 4; ++hd) {
        float w0 = r[hd * 128 + lane], w1 = r[hd * 128 + 64 + lane];
        ps[hd] = w0 * asrc[hd * 128 + lane] + w1 * asrc[hd * 128 + 64 + lane];
        pd[hd] = w0 * adst[hd * 128 + lane] + w1 * adst[hd * 128 + 64 + lane];
    }
#pragma unroll
    for (int off = 32; off > 0; off >>= 1) {
#pragma unroll
        for (int hd = 0; hd < 4; ++hd) {
            ps[hd] += __shfl_down(ps[hd], off);
            pd[hd] += __shfl_down(pd[hd], off);
        }
    }
    if (lane == 0) {
#pragma unroll
        for (int hd = 0; hd < 4; ++hd) { AS[node * 4 + hd] = ps[hd]; AD[node * 4 + hd] = pd[hd]; }
    }
}

__device__ __forceinline__ int decode_src(int eid, const int* __restrict__ edge0) {
    if (eid < BE) { int b = eid / E_EDGES; return edge0[eid - b * E_EDGES] + b * N_NODES; }
    return eid - BE;
}

// ------- per-node ONLINE-softmax attention + aggregate (one wave / node) -------
// batch<->XCD affinity: d = (bid&7)*5000 + (bid>>3)*4 + wid.
// If fcw != nullptr: fuse final FC (relu -> 6-dim projection) and write out6.
__global__ __launch_bounds__(256) void gat_aggregate(const float* __restrict__ wh,
                                                     const float* __restrict__ AS, const float* __restrict__ AD,
                                                     const int* __restrict__ offs, const int* __restrict__ esort,
                                                     const int* __restrict__ edge0, const float* __restrict__ bias,
                                                     float* __restrict__ outf,
                                                     const float* __restrict__ fcw, const float* __restrict__ fcb,
                                                     float* __restrict__ out6) {
    const int lane = threadIdx.x & 63;
    const int bid = blockIdx.x;
    const int d = (bid & 7) * N_NODES + (bid >> 3) * 4 + (threadIdx.x >> 6);
    const int e0 = offs[d], e1 = offs[d + 1];
    const fx4 ad4 = *(const fx4*)&AD[d * 4];
    float mx0 = -1e30f, mx1 = -1e30f, mx2 = -1e30f, mx3 = -1e30f;
    float den0 = 0.f, den1 = 0.f, den2 = 0.f, den3 = 0.f;
    float acc[8] = {0.f, 0.f, 0.f, 0.f, 0.f, 0.f, 0.f, 0.f};
    for (int e = e0; e < e1; ++e) {
        const int src = decode_src(esort[e], edge0);
        const fx4 as4 = *(const fx4*)&AS[src * 4];
        float v0 = as4.x + ad4.x; v0 = v0 > 0.f ? v0 : 0.2f * v0;
        float v1 = as4.y + ad4.y; v1 = v1 > 0.f ? v1 : 0.2f * v1;
        float v2 = as4.z + ad4.z; v2 = v2 > 0.f ? v2 : 0.2f * v2;
        float v3 = as4.w + ad4.w; v3 = v3 > 0.f ? v3 : 0.2f * v3;
        const float n0 = fmaxf(mx0, v0), n1 = fmaxf(mx1, v1), n2 = fmaxf(mx2, v2), n3 = fmaxf(mx3, v3);
        const float c0 = __expf(mx0 - n0), c1 = __expf(mx1 - n1), c2 = __expf(mx2 - n2), c3 = __expf(mx3 - n3);
        const float ex0 = __expf(v0 - n0), ex1 = __expf(v1 - n1), ex2 = __expf(v2 - n2), ex3 = __expf(v3 - n3);
        mx0 = n0; mx1 = n1; mx2 = n2; mx3 = n3;
        den0 = den0 * c0 + ex0; den1 = den1 * c1 + ex1;
        den2 = den2 * c2 + ex2; den3 = den3 * c3 + ex3;
        const float* wr = wh + (size_t)src * 512;
        acc[0] = acc[0] * c0 + ex0 * wr[lane];        acc[1] = acc[1] * c0 + ex0 * wr[64 + lane];
        acc[2] = acc[2] * c1 + ex1 * wr[128 + lane];  acc[3] = acc[3] * c1 + ex1 * wr[192 + lane];
        acc[4] = acc[4] * c2 + ex2 * wr[256 + lane];  acc[5] = acc[5] * c2 + ex2 * wr[320 + lane];
        acc[6] = acc[6] * c3 + ex3 * wr[384 + lane];  acc[7] = acc[7] * c3 + ex3 * wr[448 + lane];
    }
    den0 += 1e-16f; den1 += 1e-16f; den2 += 1e-16f; den3 += 1e-16f;
    const float o0r = 0.25f * (acc[0] / den0 + acc[2] / den1 + acc[4] / den2 + acc[6] / den3) + bias[lane];
    const float o1r = 0.25f * (acc[1] / den0 + acc[3] / den1 + acc[5] / den2 + acc[7] / den3) + bias[64 + lane];
    const float o0 = fmaxf(o0r, 0.f);
    const float o1 = fmaxf(o1r, 0.f);
    if (fcw == nullptr) {
        outf[(size_t)d * 128 + lane] = o0;
        outf[(size_t)d * 128 + 64 + lane] = o1;
    } else {
        float p[6];
#pragma unroll
        for (int m = 0; m < 6; ++m) p[m] = o0 * fcw[m * 128 + lane] + o1 * fcw[m * 128 + 64 + lane];
#pragma unroll
        for (int off = 32; off > 0; off >>= 1) {
#pragma unroll
            for (int m = 0; m < 6; ++m) p[m] += __shfl_down(p[m], off);
        }
        if (lane == 0) {
#pragma unroll
            for (int m = 0; m < 6; ++m) out6[(size_t)d * 6 + m] = p[m] + fcb[m];
        }
    }
}

extern "C" void kernel_launch(void* const* d_in, const int* in_sizes, int n_in,
                              void* d_out, int out_size, void* d_ws, size_t ws_size,
                              hipStream_t stream) {
    const float* x = (const float*)d_in[0];
    const float* wih0 = (const float*)d_in[1];
    const float* whh0 = (const float*)d_in[2];
    const float* bih0 = (const float*)d_in[3];
    const float* bhh0 = (const float*)d_in[4];
    const float* wih1 = (const float*)d_in[5];
    const float* whh1 = (const float*)d_in[6];
    const float* bih1 = (const float*)d_in[7];
    const float* bhh1 = (const float*)d_in[8];
    const float* g1w = (const float*)d_in[9];
    const float* g1as = (const float*)d_in[10];
    const float* g1ad = (const float*)d_in[11];
    const float* g1b = (const float*)d_in[12];
    const float* g2w = (const float*)d_in[13];
    const float* g2as = (const float*)d_in[14];
    const float* g2ad = (const float*)d_in[15];
    const float* g2b = (const float*)d_in[16];
    const float* fcw = (const float*)d_in[17];
    const float* fcb = (const float*)d_in[18];
    const int* eidx = (const int*)d_in[19];
    const int* edge0 = eidx;
    const int* edge1 = eidx + E_EDGES;

    char* ws = (char*)d_ws;
    float* H0 = (float*)ws;                               // 40000*128 f32
    float* H1 = (float*)(ws + 20480000);                  // 40000*128 f32
    float* WH = (float*)(ws + 40960000);                  // 40000*512 f32
    float* AS = (float*)(ws + 122880000);                 // 40000*4 f32
    float* AD = (float*)(ws + 123520000);                 // 40000*4 f32
    short* PK = (short*)(ws + 124160000);                 // 290816 bf16 packed weights
    int* OFFS = (int*)(ws + 124765184);                   // 40001 int
    int* CURS = (int*)(ws + 124925248);                   // 40000 int (also cnt)
    int* ESORT = (int*)(ws + 125085248);                  // 680000 int

    hipMemsetAsync(CURS, 0, BN_TOTAL * sizeof(int), stream);
    pack_w<<<1136, 256, 0, stream>>>(wih0, whh0, wih1, whh1, g1w, g2w, PK);
    csr_count<<<(NE + 255) / 256, 256, 0, stream>>>(edge1, CURS);
    csr_scan<<<1, 1024, 0, stream>>>(CURS, OFFS, CURS);
    csr_fill<<<(NE + 255) / 256, 256, 0, stream>>>(edge1, CURS, ESORT);

    gru_mfma<<<625, 512, 0, stream>>>(x, PK, bih0, bhh0, bih1, bhh1, H0);

    dim3 gg(313, 4);
    gat_gemm<<<gg, 256, 0, stream>>>(H0, PK + 159744, WH);
    gat_alpha<<<10000, 256, 0, stream>>>(WH, g1as, g1ad, AS, AD);
    gat_aggregate<<<10000, 256, 0, stream>>>(WH, AS, AD, OFFS, ESORT, edge0, g1b, H1,
                                             nullptr, nullptr, nullptr);

    gat_gemm<<<gg, 256, 0, stream>>>(H1, PK + 225280, WH);
    gat_alpha<<<10000, 256, 0, stream>>>(WH, g2as, g2ad, AS, AD);
    gat_aggregate<<<10000, 256, 0, stream>>>(WH, AS, AD, OFFS, ESORT, edge0, g2b, nullptr,
                                             fcw, fcb, (float*)d_out);
}

// Round 8
// 1303.933 us; speedup vs baseline: 4.8126x; 1.0342x over previous
//
#include <hip/hip_runtime.h>
#include <math.h>

#define T_STEPS 24
#define F_IN 10
#define HDIM 128
#define E_EDGES 80000
#define B_BATCH 8
#define N_NODES 5000
#define BN_TOTAL 40000
#define BE 640000
#define NE 680000

typedef __attribute__((ext_vector_type(8))) short s16x8;
typedef __attribute__((ext_vector_type(4))) short s16x4;
typedef __attribute__((ext_vector_type(4))) float fx4;
typedef __attribute__((ext_vector_type(2))) float fx2;
typedef __attribute__((ext_vector_type(4))) unsigned int ux4;
typedef __attribute__((ext_vector_type(2))) unsigned int ux2;

__device__ __forceinline__ float sigmoidf_(float v) { return 1.f / (1.f + __expf(-v)); }
__device__ __forceinline__ float tanhf_(float v) { float e = __expf(2.f * v); return 1.f - 2.f / (e + 1.f); }

__device__ __forceinline__ short f2b(float f) {
    unsigned u = __float_as_uint(f);
    unsigned r = (u + 0x7fffu + ((u >> 16) & 1u)) >> 16;
    return (short)r;
}
// packed bf16 convert: dst = {lo=bf16(a), hi=bf16(b)}, RNE (matches f2b)
__device__ __forceinline__ unsigned int pkbf(float a, float b) {
    unsigned int r;
    asm("v_cvt_pk_bf16_f32 %0, %1, %2" : "=v"(r) : "v"(a), "v"(b));
    return r;
}

#define VMW0 asm volatile("s_waitcnt vmcnt(0)" ::: "memory")

// ---------------- pack weights into MFMA A-fragment order (bf16), nf-major ----------------
// shorts: [0,49152) hh0 ; [49152,98304) hh1 ; [98304,147456) ih1 ; [147456,159744) ih0(K pad 10->32)
//         [159744,225280) g1w ; [225280,290816) g2w
__global__ void pack_w(const float* __restrict__ wih0, const float* __restrict__ whh0,
                       const float* __restrict__ wih1, const float* __restrict__ whh1,
                       const float* __restrict__ g1w, const float* __restrict__ g2w,
                       short* __restrict__ pk) {
    int id = blockIdx.x * 256 + threadIdx.x;
    if (id >= 290816) return;
    if (id < 147456) {
        int mat = id / 49152, r = id % 49152;
        int nf = r / 2048, r2 = r % 2048, kf = r2 / 512, r3 = r2 % 512, lane = r3 / 8, j = r3 % 8;
        int n = nf * 16 + (lane & 15), k = kf * 32 + (lane >> 4) * 8 + j;
        const float* src = (mat == 0) ? whh0 : (mat == 1) ? whh1 : wih1;
        pk[id] = f2b(src[n * 128 + k]);
    } else if (id < 159744) {
        int r = id - 147456;
        int nf = r / 512, r2 = r % 512, lane = r2 / 8, j = r2 % 8;
        int n = nf * 16 + (lane & 15), k = (lane >> 4) * 8 + j;
        pk[id] = (k < F_IN) ? f2b(wih0[n * F_IN + k]) : (short)0;
    } else {
        const float* src = (id < 225280) ? g1w : g2w;
        int r = (id < 225280) ? (id - 159744) : (id - 225280);
        int nf = r / 2048, r2 = r % 2048, kf = r2 / 512, r3 = r2 % 512, lane = r3 / 8, j = r3 % 8;
        int n = nf * 16 + (lane & 15), k = kf * 32 + (lane >> 4) * 8 + j;
        pk[id] = f2b(src[n * 128 + k]);
    }
}

// ---------------- fused 2-layer GRU; 64 seqs/block, weights stationary ----------------
__global__ __launch_bounds__(512, 1) void gru_mfma(
    const float* __restrict__ x, const short* __restrict__ pk,
    const float* __restrict__ bih0, const float* __restrict__ bhh0,
    const float* __restrict__ bih1, const float* __restrict__ bhh1,
    float* __restrict__ temporal) {
    __shared__ __align__(16) short h1b[64 * 128];     // 16 KB
    __shared__ __align__(16) short h2b[64 * 128];     // 16 KB
    __shared__ __align__(16) short ih1s[49152];       // 96 KB
    __shared__ __align__(16) short ih0s[12288];       // 24 KB
    __shared__ __align__(16) float blds[2][4][128];   // 4 KB
    const int tid = threadIdx.x;
    const int w = tid >> 6, l = tid & 63;
    const int lm = l & 15, lk = l >> 4;
    const int jb = w * 16 + lk * 4;
    const long sb = (long)blockIdx.x * 64;

    {
        const char* src1 = (const char*)(pk + 98304);
#pragma unroll
        for (int r = 0; r < 12; ++r) {
            const int off = (w * 12 + r) * 1024;
            __builtin_amdgcn_global_load_lds(
                (const __attribute__((address_space(1))) unsigned int*)(src1 + off + l * 16),
                (__attribute__((address_space(3))) unsigned int*)((char*)ih1s + off), 16, 0, 0);
        }
        const char* src0 = (const char*)(pk + 147456);
#pragma unroll
        for (int r = 0; r < 3; ++r) {
            const int off = (w * 3 + r) * 1024;
            __builtin_amdgcn_global_load_lds(
                (const __attribute__((address_space(1))) unsigned int*)(src0 + off + l * 16),
                (__attribute__((address_space(3))) unsigned int*)((char*)ih0s + off), 16, 0, 0);
        }
    }
    if (tid < 128) {
        const int j = tid;
        blds[0][0][j] = bih0[j] + bhh0[j];
        blds[0][1][j] = bih0[128 + j] + bhh0[128 + j];
        blds[0][2][j] = bhh0[256 + j];
        blds[0][3][j] = bih0[256 + j];
    } else if (tid < 256) {
        const int j = tid - 128;
        blds[1][0][j] = bih1[j] + bhh1[j];
        blds[1][1][j] = bih1[128 + j] + bhh1[128 + j];
        blds[1][2][j] = bhh1[256 + j];
        blds[1][3][j] = bih1[256 + j];
    }
    for (int i = tid; i < 64 * 128; i += 512) { h1b[i] = 0; h2b[i] = 0; }

    // ---- recurrent weights resident in VGPRs ----
    s16x8 whh0r[3][4], whh1r[3][4];
#pragma unroll
    for (int g = 0; g < 3; ++g)
#pragma unroll
        for (int kf = 0; kf < 4; ++kf) {
            const int idx = ((((g * 8 + w) * 4) + kf) * 64 + l) * 8;
            whh0r[g][kf] = *(const s16x8*)&pk[idx];
            whh1r[g][kf] = *(const s16x8*)&pk[49152 + idx];
        }

    fx4 h1s[4], h2s[4];
#pragma unroll
    for (int mf = 0; mf < 4; ++mf) { h1s[mf] = (fx4)(0.f); h2s[mf] = (fx4)(0.f); }

    VMW0;
    __syncthreads();

    for (int tt = 0; tt < T_STEPS; ++tt) {
        // ---- x loads, converted to bf16 immediately (16 live regs) ----
        ux4 xu[4];
#pragma unroll
        for (int mf = 0; mf < 4; ++mf) {
            fx2 a0 = (fx2)(0.f), a1 = (fx2)(0.f), a2 = (fx2)(0.f), a3 = (fx2)(0.f);
            const float* xr = x + (sb + mf * 16 + lm) * (T_STEPS * F_IN) + tt * F_IN;
            if (lk == 0) {
                a0 = *(const fx2*)(xr);     a1 = *(const fx2*)(xr + 2);
                a2 = *(const fx2*)(xr + 4); a3 = *(const fx2*)(xr + 6);
            } else if (lk == 1) {
                a0 = *(const fx2*)(xr + 8);
            }
            ux4 t = { pkbf(a0.x, a0.y), pkbf(a1.x, a1.y), pkbf(a2.x, a2.y), pkbf(a3.x, a3.y) };
            xu[mf] = t;
        }
        fx4 acc[4][4];
#pragma unroll
        for (int p = 0; p < 4; ++p) {
            const fx4 bv = *(const fx4*)&blds[0][p][jb];
#pragma unroll
            for (int mf = 0; mf < 4; ++mf) acc[p][mf] = bv;
        }
        // ===== layer 0: hh0 (B = h1 old), parts r,z,nh =====
#pragma unroll
        for (int kf = 0; kf < 4; ++kf) {
            s16x8 bfr[4];
#pragma unroll
            for (int mf = 0; mf < 4; ++mf) {
                const int m = mf * 16 + lm;
                const int slot = (kf * 4 + lk) ^ (m & 7);
                bfr[mf] = *(const s16x8*)&h1b[m * 128 + slot * 8];
            }
#pragma unroll
            for (int g = 0; g < 3; ++g) {
                const int part = (g == 2) ? 2 : g;
#pragma unroll
                for (int mf = 0; mf < 4; ++mf)
                    acc[part][mf] = __builtin_amdgcn_mfma_f32_16x16x32_bf16(whh0r[g][kf], bfr[mf], acc[part][mf], 0, 0, 0);
            }
        }
        // ---- ih0 (A LDS-resident, B = x frags), parts r,z,ni ----
#pragma unroll
        for (int g = 0; g < 3; ++g) {
            const int part = (g == 2) ? 3 : g;
            const s16x8 af = *(const s16x8*)&ih0s[((g * 8 + w) * 64 + l) * 8];
#pragma unroll
            for (int mf = 0; mf < 4; ++mf)
                acc[part][mf] = __builtin_amdgcn_mfma_f32_16x16x32_bf16(af, __builtin_bit_cast(s16x8, xu[mf]), acc[part][mf], 0, 0, 0);
        }
        // ---- elementwise layer 0 -> h1 (fp32 state), pack via cvt_pk ----
        ux2 w1[4];
#pragma unroll
        for (int mf = 0; mf < 4; ++mf) {
#pragma unroll
            for (int rg = 0; rg < 4; ++rg) {
                const float r = sigmoidf_(acc[0][mf][rg]);
                const float z = sigmoidf_(acc[1][mf][rg]);
                const float n = tanhf_(acc[3][mf][rg] + r * acc[2][mf][rg]);
                h1s[mf][rg] = (1.f - z) * n + z * h1s[mf][rg];
            }
            ux2 q = { pkbf(h1s[mf][0], h1s[mf][1]), pkbf(h1s[mf][2], h1s[mf][3]) };
            w1[mf] = q;
        }
        // ===== layer 1: hh1 (B = h2 old), parts r,z,nh =====
#pragma unroll
        for (int p = 0; p < 4; ++p) {
            const fx4 bv = *(const fx4*)&blds[1][p][jb];
#pragma unroll
            for (int mf = 0; mf < 4; ++mf) acc[p][mf] = bv;
        }
#pragma unroll
        for (int kf = 0; kf < 4; ++kf) {
            s16x8 bfr[4];
#pragma unroll
            for (int mf = 0; mf < 4; ++mf) {
                const int m = mf * 16 + lm;
                const int slot = (kf * 4 + lk) ^ (m & 7);
                bfr[mf] = *(const s16x8*)&h2b[m * 128 + slot * 8];
            }
#pragma unroll
            for (int g = 0; g < 3; ++g) {
                const int part = (g == 2) ? 2 : g;
#pragma unroll
                for (int mf = 0; mf < 4; ++mf)
                    acc[part][mf] = __builtin_amdgcn_mfma_f32_16x16x32_bf16(whh1r[g][kf], bfr[mf], acc[part][mf], 0, 0, 0);
            }
        }
        __syncthreads();   // all reads of h1b(old)/h2b(old) complete
#pragma unroll
        for (int mf = 0; mf < 4; ++mf) {
            const int m = mf * 16 + lm;
            const int slot = (jb >> 3) ^ (m & 7);
            *(ux2*)&h1b[m * 128 + slot * 8 + (jb & 7)] = w1[mf];
        }
        __syncthreads();   // h1 new visible
        // ===== layer 1: ih1 (A LDS-resident, B = h1 new), parts r,z,ni =====
#pragma unroll
        for (int kf = 0; kf < 4; ++kf) {
            s16x8 bfr[4];
#pragma unroll
            for (int mf = 0; mf < 4; ++mf) {
                const int m = mf * 16 + lm;
                const int slot = (kf * 4 + lk) ^ (m & 7);
                bfr[mf] = *(const s16x8*)&h1b[m * 128 + slot * 8];
            }
#pragma unroll
            for (int g = 0; g < 3; ++g) {
                const int part = (g == 2) ? 3 : g;
                const s16x8 af = *(const s16x8*)&ih1s[((((g * 8 + w) * 4) + kf) * 64 + l) * 8];
#pragma unroll
                for (int mf = 0; mf < 4; ++mf)
                    acc[part][mf] = __builtin_amdgcn_mfma_f32_16x16x32_bf16(af, bfr[mf], acc[part][mf], 0, 0, 0);
            }
        }
        // ---- elementwise layer 1 -> h2, publish ----
#pragma unroll
        for (int mf = 0; mf < 4; ++mf) {
#pragma unroll
            for (int rg = 0; rg < 4; ++rg) {
                const float r = sigmoidf_(acc[0][mf][rg]);
                const float z = sigmoidf_(acc[1][mf][rg]);
                const float n = tanhf_(acc[3][mf][rg] + r * acc[2][mf][rg]);
                h2s[mf][rg] = (1.f - z) * n + z * h2s[mf][rg];
            }
            const int m = mf * 16 + lm;
            const int slot = (jb >> 3) ^ (m & 7);
            ux2 q = { pkbf(h2s[mf][0], h2s[mf][1]), pkbf(h2s[mf][2], h2s[mf][3]) };
            *(ux2*)&h2b[m * 128 + slot * 8 + (jb & 7)] = q;
        }
        __syncthreads();   // h2 new visible for next step
    }
#pragma unroll
    for (int mf = 0; mf < 4; ++mf) {
        const long m = sb + mf * 16 + lm;
        *(fx4*)&temporal[m * 128 + jb] = h2s[mf];
    }
}

// ---------------- CSR build ----------------
__global__ void csr_count(const int* __restrict__ edge1, int* __restrict__ cnt) {
    int e = blockIdx.x * 256 + threadIdx.x;
    if (e >= NE) return;
    int d;
    if (e < BE) { int b = e / E_EDGES; d = edge1[e - b * E_EDGES] + b * N_NODES; }
    else d = e - BE;
    atomicAdd(&cnt[d], 1);
}

__global__ void csr_scan(const int* cnt, int* offs, int* curs) {
    __shared__ int part[1024];
    const int t = threadIdx.x;
    const int base = t * 40;
    int end = base + 40; if (end > BN_TOTAL) end = BN_TOTAL;
    int s = 0;
    for (int i = base; i < end; ++i) s += cnt[i];
    part[t] = s;
    __syncthreads();
    for (int off = 1; off < 1024; off <<= 1) {
        int v = (t >= off) ? part[t - off] : 0;
        __syncthreads();
        part[t] += v;
        __syncthreads();
    }
    int run = part[t] - s;
    for (int i = base; i < end; ++i) {
        int c = cnt[i];
        offs[i] = run; curs[i] = run; run += c;
    }
    if (t == 1023) offs[BN_TOTAL] = NE;
}

__global__ void csr_fill(const int* __restrict__ edge1, int* __restrict__ curs, int* __restrict__ esort) {
    int e = blockIdx.x * 256 + threadIdx.x;
    if (e >= NE) return;
    int d;
    if (e < BE) { int b = e / E_EDGES; d = edge1[e - b * E_EDGES] + b * N_NODES; }
    else d = e - BE;
    int pos = atomicAdd(&curs[d], 1);
    esort[pos] = e;
}

// ------- GAT: wh = feat @ W.T via MFMA (128 rows x 128 cols = one head per block) -------
// alpha fused: block holds ALL of head (j0>>7)'s columns for its 128 rows.
__global__ __launch_bounds__(256, 2) void gat_gemm(const float* __restrict__ feat,
                                                   const short* __restrict__ pkg,
                                                   const float* __restrict__ asrc,
                                                   const float* __restrict__ adst,
                                                   float* __restrict__ wh,
                                                   float* __restrict__ AS, float* __restrict__ AD) {
    __shared__ __align__(16) short fb[128 * 128];   // 32 KB bf16, XOR-swizzled
    __shared__ float reda[4][128];
    __shared__ float redb[4][128];
    const int tid = threadIdx.x;
    const int w = tid >> 6, l = tid & 63;
    const int lm = l & 15, lk = l >> 4;
    const int i0 = blockIdx.x * 128;
    const int j0 = blockIdx.y * 128;     // == head*128
#pragma unroll
    for (int it = 0; it < 16; ++it) {
        const int idx = it * 256 + tid;
        const int r = idx >> 5, kq = idx & 31;
        fx4 v = (fx4)(0.f);
        const int row = i0 + r;
        if (row < BN_TOTAL) v = *(const fx4*)&feat[(size_t)row * 128 + kq * 4];
        const int slot = (kq >> 1) ^ (r & 7);
        ux2 pv = { pkbf(v.x, v.y), pkbf(v.z, v.w) };
        *(ux2*)&fb[r * 128 + slot * 8 + (kq & 1) * 4] = pv;
    }
    __syncthreads();
    fx4 acc[2][8];
#pragma unroll
    for (int jf = 0; jf < 2; ++jf)
#pragma unroll
        for (int mf = 0; mf < 8; ++mf) acc[jf][mf] = (fx4)(0.f);
#pragma unroll
    for (int kf = 0; kf < 4; ++kf) {
        s16x8 bfr[8];
#pragma unroll
        for (int mf = 0; mf < 8; ++mf) {
            const int m = mf * 16 + lm;
            const int slot = (kf * 4 + lk) ^ (m & 7);
            bfr[mf] = *(const s16x8*)&fb[m * 128 + slot * 8];
        }
#pragma unroll
        for (int jf = 0; jf < 2; ++jf) {
            const int nf = (j0 >> 4) + w * 2 + jf;
            const s16x8 af = *(const s16x8*)&pkg[((nf * 4 + kf) * 64 + l) * 8];
#pragma unroll
            for (int mf = 0; mf < 8; ++mf)
                acc[jf][mf] = __builtin_amdgcn_mfma_f32_16x16x32_bf16(af, bfr[mf], acc[jf][mf], 0, 0, 0);
        }
    }
    // ---- write wh + fused alpha partials ----
    float ps[8], pd[8];
#pragma unroll
    for (int mf = 0; mf < 8; ++mf) { ps[mf] = 0.f; pd[mf] = 0.f; }
#pragma unroll
    for (int jf = 0; jf < 2; ++jf) {
        const int cb = w * 32 + jf * 16 + lk * 4;    // col within head
        const fx4 s4 = *(const fx4*)&asrc[j0 + cb];
        const fx4 d4 = *(const fx4*)&adst[j0 + cb];
        const int nb = j0 + cb;
#pragma unroll
        for (int mf = 0; mf < 8; ++mf) {
            const int m = i0 + mf * 16 + lm;
            const fx4 a = acc[jf][mf];
            if (m < BN_TOTAL) *(fx4*)&wh[(size_t)m * 512 + nb] = a;
            ps[mf] += a.x * s4.x + a.y * s4.y + a.z * s4.z + a.w * s4.w;
            pd[mf] += a.x * d4.x + a.y * d4.y + a.z * d4.z + a.w * d4.w;
        }
    }
#pragma unroll
    for (int off = 16; off <= 32; off <<= 1) {
#pragma unroll
        for (int mf = 0; mf < 8; ++mf) {
            ps[mf] += __shfl_xor(ps[mf], off);
            pd[mf] += __shfl_xor(pd[mf], off);
        }
    }
    if (lk == 0) {
#pragma unroll
        for (int mf = 0; mf < 8; ++mf) {
            reda[w][mf * 16 + lm] = ps[mf];
            redb[w][mf * 16 + lm] = pd[mf];
        }
    }
    __syncthreads();
    if (tid < 128) {
        const int row = i0 + tid;
        if (row < BN_TOTAL) {
            const float a = reda[0][tid] + reda[1][tid] + reda[2][tid] + reda[3][tid];
            const float b = redb[0][tid] + redb[1][tid] + redb[2][tid] + redb[3][tid];
            AS[row * 4 + (j0 >> 7)] = a;
            AD[row * 4 + (j0 >> 7)] = b;
        }
    }
}

__device__ __forceinline__ int decode_src(int eid, const int* __restrict__ edge0) {
    if (eid < BE) { int b = eid / E_EDGES; return edge0[eid - b * E_EDGES] + b * N_NODES; }
    return eid - BE;
}

// ------- per-node ONLINE-softmax attention + aggregate (one wave / node) -------
__global__ __launch_bounds__(256) void gat_aggregate(const float* __restrict__ wh,
                                                     const float* __restrict__ AS, const float* __restrict__ AD,
                                                     const int* __restrict__ offs, const int* __restrict__ esort,
                                                     const int* __restrict__ edge0, const float* __restrict__ bias,
                                                     float* __restrict__ outf,
                                                     const float* __restrict__ fcw, const float* __restrict__ fcb,
                                                     float* __restrict__ out6) {
    const int lane = threadIdx.x & 63;
    const int bid = blockIdx.x;
    const int d = (bid & 7) * N_NODES + (bid >> 3) * 4 + (threadIdx.x >> 6);
    const int e0 = offs[d], e1 = offs[d + 1];
    const fx4 ad4 = *(const fx4*)&AD[d * 4];
    float mx0 = -1e30f, mx1 = -1e30f, mx2 = -1e30f, mx3 = -1e30f;
    float den0 = 0.f, den1 = 0.f, den2 = 0.f, den3 = 0.f;
    float acc[8] = {0.f, 0.f, 0.f, 0.f, 0.f, 0.f, 0.f, 0.f};
    for (int e = e0; e < e1; ++e) {
        const int src = decode_src(esort[e], edge0);
        const fx4 as4 = *(const fx4*)&AS[src * 4];
        float v0 = as4.x + ad4.x; v0 = v0 > 0.f ? v0 : 0.2f * v0;
        float v1 = as4.y + ad4.y; v1 = v1 > 0.f ? v1 : 0.2f * v1;
        float v2 = as4.z + ad4.z; v2 = v2 > 0.f ? v2 : 0.2f * v2;
        float v3 = as4.w + ad4.w; v3 = v3 > 0.f ? v3 : 0.2f * v3;
        const float n0 = fmaxf(mx0, v0), n1 = fmaxf(mx1, v1), n2 = fmaxf(mx2, v2), n3 = fmaxf(mx3, v3);
        const float c0 = __expf(mx0 - n0), c1 = __expf(mx1 - n1), c2 = __expf(mx2 - n2), c3 = __expf(mx3 - n3);
        const float ex0 = __expf(v0 - n0), ex1 = __expf(v1 - n1), ex2 = __expf(v2 - n2), ex3 = __expf(v3 - n3);
        mx0 = n0; mx1 = n1; mx2 = n2; mx3 = n3;
        den0 = den0 * c0 + ex0; den1 = den1 * c1 + ex1;
        den2 = den2 * c2 + ex2; den3 = den3 * c3 + ex3;
        const float* wr = wh + (size_t)src * 512;
        acc[0] = acc[0] * c0 + ex0 * wr[lane];        acc[1] = acc[1] * c0 + ex0 * wr[64 + lane];
        acc[2] = acc[2] * c1 + ex1 * wr[128 + lane];  acc[3] = acc[3] * c1 + ex1 * wr[192 + lane];
        acc[4] = acc[4] * c2 + ex2 * wr[256 + lane];  acc[5] = acc[5] * c2 + ex2 * wr[320 + lane];
        acc[6] = acc[6] * c3 + ex3 * wr[384 + lane];  acc[7] = acc[7] * c3 + ex3 * wr[448 + lane];
    }
    den0 += 1e-16f; den1 += 1e-16f; den2 += 1e-16f; den3 += 1e-16f;
    const float o0r = 0.25f * (acc[0] / den0 + acc[2] / den1 + acc[4] / den2 + acc[6] / den3) + bias[lane];
    const float o1r = 0.25f * (acc[1] / den0 + acc[3] / den1 + acc[5] / den2 + acc[7] / den3) + bias[64 + lane];
    const float o0 = fmaxf(o0r, 0.f);
    const float o1 = fmaxf(o1r, 0.f);
    if (fcw == nullptr) {
        outf[(size_t)d * 128 + lane] = o0;
        outf[(size_t)d * 128 + 64 + lane] = o1;
    } else {
        float p[6];
#pragma unroll
        for (int m = 0; m < 6; ++m) p[m] = o0 * fcw[m * 128 + lane] + o1 * fcw[m * 128 + 64 + lane];
#pragma unroll
        for (int off = 32; off > 0; off >>= 1) {
#pragma unroll
            for (int m = 0; m < 6; ++m) p[m] += __shfl_down(p[m], off);
        }
        if (lane == 0) {
#pragma unroll
            for (int m = 0; m < 6; ++m) out6[(size_t)d * 6 + m] = p[m] + fcb[m];
        }
    }
}

extern "C" void kernel_launch(void* const* d_in, const int* in_sizes, int n_in,
                              void* d_out, int out_size, void* d_ws, size_t ws_size,
                              hipStream_t stream) {
    const float* x = (const float*)d_in[0];
    const float* wih0 = (const float*)d_in[1];
    const float* whh0 = (const float*)d_in[2];
    const float* bih0 = (const float*)d_in[3];
    const float* bhh0 = (const float*)d_in[4];
    const float* wih1 = (const float*)d_in[5];
    const float* whh1 = (const float*)d_in[6];
    const float* bih1 = (const float*)d_in[7];
    const float* bhh1 = (const float*)d_in[8];
    const float* g1w = (const float*)d_in[9];
    const float* g1as = (const float*)d_in[10];
    const float* g1ad = (const float*)d_in[11];
    const float* g1b = (const float*)d_in[12];
    const float* g2w = (const float*)d_in[13];
    const float* g2as = (const float*)d_in[14];
    const float* g2ad = (const float*)d_in[15];
    const float* g2b = (const float*)d_in[16];
    const float* fcw = (const float*)d_in[17];
    const float* fcb = (const float*)d_in[18];
    const int* eidx = (const int*)d_in[19];
    const int* edge0 = eidx;
    const int* edge1 = eidx + E_EDGES;

    char* ws = (char*)d_ws;
    float* H0 = (float*)ws;                               // 40000*128 f32
    float* H1 = (float*)(ws + 20480000);                  // 40000*128 f32
    float* WH = (float*)(ws + 40960000);                  // 40000*512 f32
    float* AS = (float*)(ws + 122880000);                 // 40000*4 f32
    float* AD = (float*)(ws + 123520000);                 // 40000*4 f32
    short* PK = (short*)(ws + 124160000);                 // 290816 bf16 packed weights
    int* OFFS = (int*)(ws + 124765184);                   // 40001 int
    int* CURS = (int*)(ws + 124925248);                   // 40000 int (also cnt)
    int* ESORT = (int*)(ws + 125085248);                  // 680000 int

    hipMemsetAsync(CURS, 0, BN_TOTAL * sizeof(int), stream);
    pack_w<<<1136, 256, 0, stream>>>(wih0, whh0, wih1, whh1, g1w, g2w, PK);
    csr_count<<<(NE + 255) / 256, 256, 0, stream>>>(edge1, CURS);
    csr_scan<<<1, 1024, 0, stream>>>(CURS, OFFS, CURS);
    csr_fill<<<(NE + 255) / 256, 256, 0, stream>>>(edge1, CURS, ESORT);

    gru_mfma<<<625, 512, 0, stream>>>(x, PK, bih0, bhh0, bih1, bhh1, H0);

    dim3 gg(313, 4);
    gat_gemm<<<gg, 256, 0, stream>>>(H0, PK + 159744, g1as, g1ad, WH, AS, AD);
    gat_aggregate<<<10000, 256, 0, stream>>>(WH, AS, AD, OFFS, ESORT, edge0, g1b, H1,
                                             nullptr, nullptr, nullptr);

    gat_gemm<<<gg, 256, 0, stream>>>(H1, PK + 225280, g2as, g2ad, WH, AS, AD);
    gat_aggregate<<<10000, 256, 0, stream>>>(WH, AS, AD, OFFS, ESORT, edge0, g2b, nullptr,
                                             fcw, fcb, (float*)d_out);
}